// Round 1
// baseline (727.228 us; speedup 1.0000x reference)
//
#include <hip/hip_runtime.h>

#define N_NODES 100000

// ---------------- degree / norm ----------------

__global__ __launch_bounds__(256) void count_deg_k(const int* __restrict__ dst,
                                                   int* __restrict__ deg, int E) {
    int e = blockIdx.x * 256 + threadIdx.x;
    if (e < E) atomicAdd(&deg[dst[e]], 1);
}

__global__ __launch_bounds__(256) void dinv_k(const int* __restrict__ deg,
                                              float* __restrict__ dinv) {
    int v = blockIdx.x * 256 + threadIdx.x;
    if (v < N_NODES) dinv[v] = rsqrtf((float)deg[v] + 1.0f);  // +1 = self-loop
}

// ---------------- GEMM1: h1[N,64] = x[N,128] @ W1[128,64] ----------------
// grid = N/32 = 3125 blocks, 256 thr = 4 waves, 8 rows per wave.
// Wave-uniform row -> x loads are scalar; W1 staged in LDS.

__global__ __launch_bounds__(256) void gemm1_k(const float* __restrict__ x,
                                               const float* __restrict__ W1,
                                               float* __restrict__ h1) {
    __shared__ float Ws[128 * 64];
    for (int i = threadIdx.x; i < 128 * 64; i += 256) Ws[i] = W1[i];
    __syncthreads();
    int lane = threadIdx.x & 63;
    int base = (blockIdx.x * 4 + (threadIdx.x >> 6)) * 8;
    for (int rr = 0; rr < 8; ++rr) {
        int row = __builtin_amdgcn_readfirstlane(base + rr);
        const float* xr = x + row * 128;
        float acc = 0.f;
#pragma unroll
        for (int k = 0; k < 128; ++k)
            acc = fmaf(xr[k], Ws[k * 64 + lane], acc);
        h1[row * 64 + lane] = acc;
    }
}

// ---------------- scatter-add: agg[dst] += norm * h[src] ----------------
// One wave per edge (64 feats): e is wave-uniform -> scalar src/dst/dinv loads,
// coalesced 256B gather + coalesced atomics. Edges [E, E+N) are self-loops.

__global__ __launch_bounds__(256) void scatter64_k(const int* __restrict__ src,
        const int* __restrict__ dst, const float* __restrict__ dinv,
        const float* __restrict__ h, float* __restrict__ agg, int E) {
    unsigned int gid = blockIdx.x * 256u + threadIdx.x;
    int e = gid >> 6;
    int f = gid & 63;
    if (e >= E + N_NODES) return;
    int s, d;
    if (e < E) { s = src[e]; d = dst[e]; }
    else       { s = d = e - E; }
    float w = dinv[s] * dinv[d];
    atomicAdd(&agg[d * 64 + f], w * h[s * 64 + f]);
}

__global__ __launch_bounds__(256) void scatter32_k(const int* __restrict__ src,
        const int* __restrict__ dst, const float* __restrict__ dinv,
        const float* __restrict__ h, float* __restrict__ agg, int E) {
    unsigned int gid = blockIdx.x * 256u + threadIdx.x;
    int e = gid >> 5;
    int f = gid & 31;
    if (e >= E + N_NODES) return;
    int s, d;
    if (e < E) { s = src[e]; d = dst[e]; }
    else       { s = d = e - E; }
    float w = dinv[s] * dinv[d];
    atomicAdd(&agg[d * 32 + f], w * h[s * 32 + f]);
}

// ---------------- GEMM2: h2[N,32] = relu(agg1[N,64] + b1) @ W2[64,32] ----

__global__ __launch_bounds__(256) void gemm2_k(const float* __restrict__ agg1,
        const float* __restrict__ b1, const float* __restrict__ W2,
        float* __restrict__ h2) {
    __shared__ float Ws[64 * 32];
    __shared__ float Rs[8][64];
    for (int i = threadIdx.x; i < 64 * 32; i += 256) Ws[i] = W2[i];
    int rbase = blockIdx.x * 8;
    for (int i = threadIdx.x; i < 8 * 64; i += 256) {
        int r = i >> 6, k = i & 63;
        Rs[r][k] = fmaxf(agg1[(rbase + r) * 64 + k] + b1[k], 0.f);
    }
    __syncthreads();
    int c = threadIdx.x & 31, r = threadIdx.x >> 5;
    float acc = 0.f;
#pragma unroll
    for (int k = 0; k < 64; ++k)
        acc = fmaf(Rs[r][k], Ws[k * 32 + c], acc);
    h2[(rbase + r) * 32 + c] = acc;
}

// ---------------- final: out = relu(agg2 + b2) @ Wfc + bfc ----------------

__global__ __launch_bounds__(256) void final_k(const float* __restrict__ agg2,
        const float* __restrict__ b2, const float* __restrict__ Wfc,
        const float* __restrict__ bfc, float* __restrict__ out) {
    int v = blockIdx.x * 256 + threadIdx.x;
    if (v >= N_NODES) return;
    const float* row = agg2 + v * 32;
    float acc = 0.f;
#pragma unroll
    for (int k = 0; k < 32; ++k)
        acc = fmaf(fmaxf(row[k] + b2[k], 0.f), Wfc[k], acc);
    out[v] = acc + bfc[0];
}

extern "C" void kernel_launch(void* const* d_in, const int* in_sizes, int n_in,
                              void* d_out, int out_size, void* d_ws, size_t ws_size,
                              hipStream_t stream) {
    const float* x   = (const float*)d_in[0];
    const int*   ei  = (const int*)d_in[1];
    const float* W1  = (const float*)d_in[2];
    const float* b1  = (const float*)d_in[3];
    const float* W2  = (const float*)d_in[4];
    const float* b2  = (const float*)d_in[5];
    const float* Wfc = (const float*)d_in[6];
    const float* bfc = (const float*)d_in[7];
    float* out = (float*)d_out;

    const int E = in_sizes[1] / 2;
    const int* src = ei;
    const int* dst = ei + E;

    // workspace layout (floats): deg(N int) | dinv(N) | h(N*64) | agg(N*64)
    float* ws   = (float*)d_ws;
    int*   deg  = (int*)ws;
    float* dinv = ws + N_NODES;
    float* h1   = ws + 2 * N_NODES;
    float* agg1 = h1 + N_NODES * 64;
    float* h2   = h1;    // reuse (N*32) after scatter64 is done with h1
    float* agg2 = agg1;  // reuse (N*32) after gemm2 is done with agg1

    hipMemsetAsync(deg, 0, N_NODES * sizeof(int), stream);
    count_deg_k<<<(E + 255) / 256, 256, 0, stream>>>(dst, deg, E);
    dinv_k<<<(N_NODES + 255) / 256, 256, 0, stream>>>(deg, dinv);

    gemm1_k<<<N_NODES / 32, 256, 0, stream>>>(x, W1, h1);

    hipMemsetAsync(agg1, 0, (size_t)N_NODES * 64 * sizeof(float), stream);
    {
        long tot = (long)(E + N_NODES) * 64;
        scatter64_k<<<(int)((tot + 255) / 256), 256, 0, stream>>>(src, dst, dinv, h1, agg1, E);
    }

    gemm2_k<<<N_NODES / 8, 256, 0, stream>>>(agg1, b1, W2, h2);

    hipMemsetAsync(agg2, 0, (size_t)N_NODES * 32 * sizeof(float), stream);
    {
        long tot = (long)(E + N_NODES) * 32;
        scatter32_k<<<(int)((tot + 255) / 256), 256, 0, stream>>>(src, dst, dinv, h2, agg2, E);
    }

    final_k<<<(N_NODES + 255) / 256, 256, 0, stream>>>(agg2, b2, Wfc, bfc, out);
}

// Round 2
// 518.270 us; speedup vs baseline: 1.4032x; 1.4032x over previous
//
#include <hip/hip_runtime.h>

#define N_NODES 100000

// ============ degree / norm ============

__global__ __launch_bounds__(256) void count_deg_k(const int* __restrict__ dst,
                                                   int* __restrict__ deg, int E) {
    int e = blockIdx.x * 256 + threadIdx.x;
    if (e < E) atomicAdd(&deg[dst[e]], 1);
}

__global__ __launch_bounds__(256) void dinv_k(const int* __restrict__ deg,
                                              float* __restrict__ dinv) {
    int v = blockIdx.x * 256 + threadIdx.x;
    if (v < N_NODES) dinv[v] = rsqrtf((float)deg[v] + 1.0f);  // +1 = self-loop
}

// ============ CSR build: offsets = exclusive scan of (deg+1) ============

__global__ __launch_bounds__(256) void blocksum_k(const int* __restrict__ deg,
                                                  int* __restrict__ blockSums) {
    __shared__ int sd[256];
    int v = blockIdx.x * 256 + threadIdx.x;
    sd[threadIdx.x] = (v < N_NODES) ? deg[v] + 1 : 0;
    __syncthreads();
    for (int s = 128; s > 0; s >>= 1) {
        if (threadIdx.x < s) sd[threadIdx.x] += sd[threadIdx.x + s];
        __syncthreads();
    }
    if (threadIdx.x == 0) blockSums[blockIdx.x] = sd[0];
}

// single block: exclusive scan of nb (<512) block sums
__global__ __launch_bounds__(256) void scanblocks_k(const int* __restrict__ blockSums,
                                                    int* __restrict__ blockOffs, int nb) {
    __shared__ int ps[256];
    int t = threadIdx.x;
    int a = (2 * t < nb) ? blockSums[2 * t] : 0;
    int b = (2 * t + 1 < nb) ? blockSums[2 * t + 1] : 0;
    ps[t] = a + b;
    __syncthreads();
    for (int off = 1; off < 256; off <<= 1) {
        int val = ps[t];
        int add = (t >= off) ? ps[t - off] : 0;
        __syncthreads();
        ps[t] = val + add;
        __syncthreads();
    }
    int excl = ps[t] - (a + b);
    if (2 * t < nb)     blockOffs[2 * t]     = excl;
    if (2 * t + 1 < nb) blockOffs[2 * t + 1] = excl + a;
}

__global__ __launch_bounds__(256) void offsets_k(const int* __restrict__ deg,
        const int* __restrict__ blockOffs, int* __restrict__ offsets) {
    __shared__ int ps[256];
    int t = threadIdx.x;
    int v = blockIdx.x * 256 + t;
    int d = (v < N_NODES) ? deg[v] + 1 : 0;
    ps[t] = d;
    __syncthreads();
    for (int off = 1; off < 256; off <<= 1) {
        int val = ps[t];
        int add = (t >= off) ? ps[t - off] : 0;
        __syncthreads();
        ps[t] = val + add;
        __syncthreads();
    }
    int incl = ps[t];
    int base = blockOffs[blockIdx.x];
    if (v < N_NODES) offsets[v] = base + incl - d;
    if (v == N_NODES - 1) offsets[N_NODES] = base + incl;
}

// fill: edges then self-loops, arbitrary order within a row
__global__ __launch_bounds__(256) void fill_k(const int* __restrict__ src,
        const int* __restrict__ dst, const int* __restrict__ offsets,
        int* __restrict__ cursor, int* __restrict__ srt_src, int E) {
    int e = blockIdx.x * 256 + threadIdx.x;
    if (e >= E + N_NODES) return;
    int s, d;
    if (e < E) { s = src[e]; d = dst[e]; }
    else       { s = d = e - E; }
    int pos = atomicAdd(&cursor[d], 1);
    srt_src[offsets[d] + pos] = s;
}

// ============ GEMM1: h1[N,64] = x[N,128] @ W1[128,64] ============

__global__ __launch_bounds__(256) void gemm1_k(const float* __restrict__ x,
                                               const float* __restrict__ W1,
                                               float* __restrict__ h1) {
    __shared__ float Ws[128 * 64];
    for (int i = threadIdx.x; i < 128 * 64; i += 256) Ws[i] = W1[i];
    __syncthreads();
    int lane = threadIdx.x & 63;
    int base = (blockIdx.x * 4 + (threadIdx.x >> 6)) * 8;
    for (int rr = 0; rr < 8; ++rr) {
        int row = __builtin_amdgcn_readfirstlane(base + rr);
        const float* xr = x + row * 128;
        float acc = 0.f;
#pragma unroll
        for (int k = 0; k < 128; ++k)
            acc = fmaf(xr[k], Ws[k * 64 + lane], acc);
        h1[row * 64 + lane] = acc;
    }
}

// ============ layer2: h2 = relu(agg(h1)+b1) @ W2  (fused) ============
// one wave per node; lane = feature (64); CSR gather; epilogue via shfl.

__global__ __launch_bounds__(256) void layer2_k(const int* __restrict__ offsets,
        const int* __restrict__ srt_src, const float* __restrict__ dinv,
        const float* __restrict__ h1, const float* __restrict__ b1,
        const float* __restrict__ W2, float* __restrict__ h2) {
    __shared__ float W2s[64 * 32];
    for (int i = threadIdx.x; i < 64 * 32; i += 256) W2s[i] = W2[i];
    __syncthreads();
    int lane = threadIdx.x & 63;
    int v = blockIdx.x * 4 + (threadIdx.x >> 6);   // grid = N/4 exactly
    float dv = dinv[v];
    int beg = offsets[v], end = offsets[v + 1];
    float acc = 0.f;
    int i = beg;
    for (; i + 1 < end; i += 2) {
        int s0 = srt_src[i], s1 = srt_src[i + 1];
        float w0 = dinv[s0] * dv, w1 = dinv[s1] * dv;
        float v0 = h1[s0 * 64 + lane], v1 = h1[s1 * 64 + lane];
        acc = fmaf(w0, v0, acc);
        acc = fmaf(w1, v1, acc);
    }
    if (i < end) {
        int s = srt_src[i];
        acc = fmaf(dinv[s] * dv, h1[s * 64 + lane], acc);
    }
    float R = fmaxf(acc + b1[lane], 0.f);
    int c = lane & 31;
    float o = 0.f;
#pragma unroll
    for (int k = 0; k < 64; ++k)
        o = fmaf(__shfl(R, k, 64), W2s[k * 32 + c], o);
    if (lane < 32) h2[v * 32 + lane] = o;
}

// ============ layer3: out = relu(agg(h2)+b2) @ Wfc + bfc  (fused) ============
// one wave per node; lanes split into 2 half-waves, 2 edges/iter.

__global__ __launch_bounds__(256) void layer3_k(const int* __restrict__ offsets,
        const int* __restrict__ srt_src, const float* __restrict__ dinv,
        const float* __restrict__ h2, const float* __restrict__ b2,
        const float* __restrict__ Wfc, const float* __restrict__ bfc,
        float* __restrict__ out) {
    int lane = threadIdx.x & 63;
    int f = lane & 31, half = lane >> 5;
    int v = blockIdx.x * 4 + (threadIdx.x >> 6);   // grid = N/4 exactly
    float dv = dinv[v];
    int beg = offsets[v], end = offsets[v + 1];
    float acc = 0.f;
    for (int i = beg + half; i < end; i += 2) {
        int s = srt_src[i];
        acc = fmaf(dinv[s] * dv, h2[s * 32 + f], acc);
    }
    acc += __shfl_xor(acc, 32, 64);                 // combine half-waves
    float p = fmaxf(acc + b2[f], 0.f) * Wfc[f];
#pragma unroll
    for (int off = 16; off; off >>= 1) p += __shfl_xor(p, off, 64);
    if (lane == 0) out[v] = p + bfc[0];
}

// ============ launch ============

extern "C" void kernel_launch(void* const* d_in, const int* in_sizes, int n_in,
                              void* d_out, int out_size, void* d_ws, size_t ws_size,
                              hipStream_t stream) {
    const float* x   = (const float*)d_in[0];
    const int*   ei  = (const int*)d_in[1];
    const float* W1  = (const float*)d_in[2];
    const float* b1  = (const float*)d_in[3];
    const float* W2  = (const float*)d_in[4];
    const float* b2  = (const float*)d_in[5];
    const float* Wfc = (const float*)d_in[6];
    const float* bfc = (const float*)d_in[7];
    float* out = (float*)d_out;

    const int E = in_sizes[1] / 2;
    const int* src = ei;
    const int* dst = ei + E;
    const int NB = (N_NODES + 255) / 256;   // 391 scan blocks

    // workspace layout
    int*   deg       = (int*)d_ws;                 // N
    int*   cursor    = deg + N_NODES;              // N
    int*   offsets   = cursor + N_NODES;           // N+1
    int*   blockSums = offsets + N_NODES + 1;      // 512
    int*   blockOffs = blockSums + 512;            // 512
    int*   srt_src   = blockOffs + 512;            // E+N
    float* dinv      = (float*)(srt_src + E + N_NODES);  // N
    float* h1        = dinv + N_NODES;             // N*64
    float* h2        = h1 + N_NODES * 64;          // N*32

    hipMemsetAsync(deg, 0, 2 * N_NODES * sizeof(int), stream);  // deg + cursor
    count_deg_k<<<(E + 255) / 256, 256, 0, stream>>>(dst, deg, E);
    dinv_k<<<NB, 256, 0, stream>>>(deg, dinv);
    blocksum_k<<<NB, 256, 0, stream>>>(deg, blockSums);
    scanblocks_k<<<1, 256, 0, stream>>>(blockSums, blockOffs, NB);
    offsets_k<<<NB, 256, 0, stream>>>(deg, blockOffs, offsets);
    fill_k<<<(E + N_NODES + 255) / 256, 256, 0, stream>>>(src, dst, offsets, cursor,
                                                          srt_src, E);

    gemm1_k<<<N_NODES / 32, 256, 0, stream>>>(x, W1, h1);

    layer2_k<<<N_NODES / 4, 256, 0, stream>>>(offsets, srt_src, dinv, h1, b1, W2, h2);
    layer3_k<<<N_NODES / 4, 256, 0, stream>>>(offsets, srt_src, dinv, h2, b2, Wfc,
                                              bfc, out);
}

// Round 3
// 459.045 us; speedup vs baseline: 1.5842x; 1.1290x over previous
//
#include <hip/hip_runtime.h>

#define N_NODES 100000
typedef unsigned int u32;
typedef unsigned short u16;

static __device__ __forceinline__ float bf2f(u16 h) {
    u32 u = ((u32)h) << 16;
    union { u32 u; float f; } c; c.u = u;
    return c.f;
}
static __device__ __forceinline__ u16 f2bf(float f) {  // round-nearest-even
    union { float f; u32 u; } c; c.f = f;
    u32 r = (c.u + 0x7fffu + ((c.u >> 16) & 1u)) >> 16;
    return (u16)r;
}

// ============ degree / norm ============

__global__ __launch_bounds__(256) void count_deg_k(const int* __restrict__ dst,
                                                   int* __restrict__ deg, int E) {
    int e = blockIdx.x * 256 + threadIdx.x;
    if (e < E) atomicAdd(&deg[dst[e]], 1);
}

__global__ __launch_bounds__(256) void dinv_k(const int* __restrict__ deg,
                                              float* __restrict__ dinv) {
    int v = blockIdx.x * 256 + threadIdx.x;
    if (v < N_NODES) dinv[v] = rsqrtf((float)deg[v] + 1.0f);  // +1 = self-loop
}

// ============ CSR build: offsets = exclusive scan of (deg+1) ============

__global__ __launch_bounds__(256) void blocksum_k(const int* __restrict__ deg,
                                                  int* __restrict__ blockSums) {
    __shared__ int sd[256];
    int v = blockIdx.x * 256 + threadIdx.x;
    sd[threadIdx.x] = (v < N_NODES) ? deg[v] + 1 : 0;
    __syncthreads();
    for (int s = 128; s > 0; s >>= 1) {
        if (threadIdx.x < s) sd[threadIdx.x] += sd[threadIdx.x + s];
        __syncthreads();
    }
    if (threadIdx.x == 0) blockSums[blockIdx.x] = sd[0];
}

__global__ __launch_bounds__(256) void scanblocks_k(const int* __restrict__ blockSums,
                                                    int* __restrict__ blockOffs, int nb) {
    __shared__ int ps[256];
    int t = threadIdx.x;
    int a = (2 * t < nb) ? blockSums[2 * t] : 0;
    int b = (2 * t + 1 < nb) ? blockSums[2 * t + 1] : 0;
    ps[t] = a + b;
    __syncthreads();
    for (int off = 1; off < 256; off <<= 1) {
        int val = ps[t];
        int add = (t >= off) ? ps[t - off] : 0;
        __syncthreads();
        ps[t] = val + add;
        __syncthreads();
    }
    int excl = ps[t] - (a + b);
    if (2 * t < nb)     blockOffs[2 * t]     = excl;
    if (2 * t + 1 < nb) blockOffs[2 * t + 1] = excl + a;
}

__global__ __launch_bounds__(256) void offsets_k(const int* __restrict__ deg,
        const int* __restrict__ blockOffs, int* __restrict__ offsets) {
    __shared__ int ps[256];
    int t = threadIdx.x;
    int v = blockIdx.x * 256 + t;
    int d = (v < N_NODES) ? deg[v] + 1 : 0;
    ps[t] = d;
    __syncthreads();
    for (int off = 1; off < 256; off <<= 1) {
        int val = ps[t];
        int add = (t >= off) ? ps[t - off] : 0;
        __syncthreads();
        ps[t] = val + add;
        __syncthreads();
    }
    int incl = ps[t];
    int base = blockOffs[blockIdx.x];
    if (v < N_NODES) offsets[v] = base + incl - d;
    if (v == N_NODES - 1) offsets[N_NODES] = base + incl;
}

__global__ __launch_bounds__(256) void fill_k(const int* __restrict__ src,
        const int* __restrict__ dst, const int* __restrict__ offsets,
        int* __restrict__ cursor, int* __restrict__ srt_src, int E) {
    int e = blockIdx.x * 256 + threadIdx.x;
    if (e >= E + N_NODES) return;
    int s, d;
    if (e < E) { s = src[e]; d = dst[e]; }
    else       { s = d = e - E; }
    int pos = atomicAdd(&cursor[d], 1);
    srt_src[offsets[d] + pos] = s;
}

// ============ GEMM1: h1b[N,64](bf16) = x[N,128] @ W1[128,64] ============

__global__ __launch_bounds__(256) void gemm1_k(const float* __restrict__ x,
                                               const float* __restrict__ W1,
                                               u16* __restrict__ h1b) {
    __shared__ float Ws[128 * 64];
    for (int i = threadIdx.x; i < 128 * 64; i += 256) Ws[i] = W1[i];
    __syncthreads();
    int lane = threadIdx.x & 63;
    int base = (blockIdx.x * 4 + (threadIdx.x >> 6)) * 8;
    for (int rr = 0; rr < 8; ++rr) {
        int row = __builtin_amdgcn_readfirstlane(base + rr);
        const float* xr = x + row * 128;
        float acc = 0.f;
#pragma unroll
        for (int k = 0; k < 128; ++k)
            acc = fmaf(xr[k], Ws[k * 64 + lane], acc);
        h1b[row * 64 + lane] = f2bf(acc);
    }
}

// ============ layer2: h2b = relu(agg(h1b)+b1) @ W2  (fused, bf16 I/O) ======
// one wave per node; half-wave per edge (2 edges in flight), lane holds a
// packed pair of features (4B load). Combine halves with shfl_xor 32.

__global__ __launch_bounds__(256) void layer2_k(const int* __restrict__ offsets,
        const int* __restrict__ srt_src, const float* __restrict__ dinv,
        const u16* __restrict__ h1b, const float* __restrict__ b1,
        const float* __restrict__ W2, u16* __restrict__ h2b) {
    __shared__ float W2s[64 * 32];
    for (int i = threadIdx.x; i < 64 * 32; i += 256) W2s[i] = W2[i];
    __syncthreads();
    int lane = threadIdx.x & 63;
    int f = lane & 31, h = lane >> 5;
    int v = blockIdx.x * 4 + (threadIdx.x >> 6);   // grid = N/4 exactly
    float dv = dinv[v];
    int beg = offsets[v], end = offsets[v + 1];
    float a0 = 0.f, a1 = 0.f;
    int i = beg + h;
    // 2x manual unroll (4 edges in flight across the wave)
    for (; i + 2 < end; i += 4) {
        int sA = srt_src[i], sB = srt_src[i + 2];
        float wA = dinv[sA] * dv, wB = dinv[sB] * dv;
        u32 pA = *((const u32*)(h1b + sA * 64) + f);
        u32 pB = *((const u32*)(h1b + sB * 64) + f);
        a0 = fmaf(wA, bf2f((u16)(pA & 0xffff)), a0);
        a1 = fmaf(wA, bf2f((u16)(pA >> 16)), a1);
        a0 = fmaf(wB, bf2f((u16)(pB & 0xffff)), a0);
        a1 = fmaf(wB, bf2f((u16)(pB >> 16)), a1);
    }
    for (; i < end; i += 2) {
        int s = srt_src[i];
        float w = dinv[s] * dv;
        u32 p = *((const u32*)(h1b + s * 64) + f);
        a0 = fmaf(w, bf2f((u16)(p & 0xffff)), a0);
        a1 = fmaf(w, bf2f((u16)(p >> 16)), a1);
    }
    a0 += __shfl_xor(a0, 32, 64);
    a1 += __shfl_xor(a1, 32, 64);
    // every lane now holds agg feats (2f, 2f+1); bias + relu
    float r0 = fmaxf(a0 + b1[2 * f], 0.f);
    float r1 = fmaxf(a1 + b1[2 * f + 1], 0.f);
    // o_c = sum_k R_k * W2[k][c], c = f; R_{2j},R_{2j+1} live on lane j
    float o = 0.f;
#pragma unroll
    for (int j = 0; j < 32; ++j) {
        float R0 = __shfl(r0, j, 64);
        float R1 = __shfl(r1, j, 64);
        o = fmaf(R0, W2s[(2 * j) * 32 + f], o);
        o = fmaf(R1, W2s[(2 * j + 1) * 32 + f], o);
    }
    if (h == 0) h2b[v * 32 + f] = f2bf(o);
}

// ============ layer3: out = relu(agg(h2b)+b2) @ Wfc + bfc  (fused) ==========
// one wave per node; quarter-wave per edge (4 edges in flight).

__global__ __launch_bounds__(256) void layer3_k(const int* __restrict__ offsets,
        const int* __restrict__ srt_src, const float* __restrict__ dinv,
        const u16* __restrict__ h2b, const float* __restrict__ b2,
        const float* __restrict__ Wfc, const float* __restrict__ bfc,
        float* __restrict__ out) {
    int lane = threadIdx.x & 63;
    int f = lane & 15, q = lane >> 4;
    int v = blockIdx.x * 4 + (threadIdx.x >> 6);   // grid = N/4 exactly
    float dv = dinv[v];
    int beg = offsets[v], end = offsets[v + 1];
    float a0 = 0.f, a1 = 0.f;
    for (int i = beg + q; i < end; i += 4) {
        int s = srt_src[i];
        float w = dinv[s] * dv;
        u32 p = *((const u32*)(h2b + s * 32) + f);
        a0 = fmaf(w, bf2f((u16)(p & 0xffff)), a0);
        a1 = fmaf(w, bf2f((u16)(p >> 16)), a1);
    }
    a0 += __shfl_xor(a0, 16, 64); a0 += __shfl_xor(a0, 32, 64);
    a1 += __shfl_xor(a1, 16, 64); a1 += __shfl_xor(a1, 32, 64);
    float p = fmaxf(a0 + b2[2 * f], 0.f) * Wfc[2 * f]
            + fmaxf(a1 + b2[2 * f + 1], 0.f) * Wfc[2 * f + 1];
#pragma unroll
    for (int off = 8; off; off >>= 1) p += __shfl_xor(p, off, 64);
    if (lane == 0) out[v] = p + bfc[0];
}

// ============ launch ============

extern "C" void kernel_launch(void* const* d_in, const int* in_sizes, int n_in,
                              void* d_out, int out_size, void* d_ws, size_t ws_size,
                              hipStream_t stream) {
    const float* x   = (const float*)d_in[0];
    const int*   ei  = (const int*)d_in[1];
    const float* W1  = (const float*)d_in[2];
    const float* b1  = (const float*)d_in[3];
    const float* W2  = (const float*)d_in[4];
    const float* b2  = (const float*)d_in[5];
    const float* Wfc = (const float*)d_in[6];
    const float* bfc = (const float*)d_in[7];
    float* out = (float*)d_out;

    const int E = in_sizes[1] / 2;
    const int* src = ei;
    const int* dst = ei + E;
    const int NB = (N_NODES + 255) / 256;

    int*   deg       = (int*)d_ws;                 // N
    int*   cursor    = deg + N_NODES;              // N
    int*   offsets   = cursor + N_NODES;           // N+1
    int*   blockSums = offsets + N_NODES + 1;      // 512
    int*   blockOffs = blockSums + 512;            // 512
    int*   srt_src   = blockOffs + 512;            // E+N
    float* dinv      = (float*)(srt_src + E + N_NODES);  // N
    u16*   h1b       = (u16*)(dinv + N_NODES);     // N*64 bf16
    u16*   h2b       = h1b + (size_t)N_NODES * 64; // N*32 bf16

    hipMemsetAsync(deg, 0, 2 * N_NODES * sizeof(int), stream);  // deg + cursor
    count_deg_k<<<(E + 255) / 256, 256, 0, stream>>>(dst, deg, E);
    dinv_k<<<NB, 256, 0, stream>>>(deg, dinv);
    blocksum_k<<<NB, 256, 0, stream>>>(deg, blockSums);
    scanblocks_k<<<1, 256, 0, stream>>>(blockSums, blockOffs, NB);
    offsets_k<<<NB, 256, 0, stream>>>(deg, blockOffs, offsets);
    fill_k<<<(E + N_NODES + 255) / 256, 256, 0, stream>>>(src, dst, offsets, cursor,
                                                          srt_src, E);

    gemm1_k<<<N_NODES / 32, 256, 0, stream>>>(x, W1, h1b);

    layer2_k<<<N_NODES / 4, 256, 0, stream>>>(offsets, srt_src, dinv, h1b, b1, W2, h2b);
    layer3_k<<<N_NODES / 4, 256, 0, stream>>>(offsets, srt_src, dinv, h2b, b2, Wfc,
                                              bfc, out);
}

// Round 4
// 433.013 us; speedup vs baseline: 1.6795x; 1.0601x over previous
//
#include <hip/hip_runtime.h>

#define N_NODES 100000
typedef unsigned int u32;
typedef unsigned short u16;

static __device__ __forceinline__ u16 f2bf(float f) {  // round-nearest-even
    union { float f; u32 u; } c; c.f = f;
    u32 r = (c.u + 0x7fffu + ((c.u >> 16) & 1u)) >> 16;
    return (u16)r;
}
// accumulate a packed pair of bf16 into two f32 accumulators
static __device__ __forceinline__ void acc2(u32 p, float& a, float& b) {
    union { u32 u; float f; } lo, hi;
    lo.u = p << 16;
    hi.u = p & 0xffff0000u;
    a += lo.f;
    b += hi.f;
}

// ============ degree / norm ============

__global__ __launch_bounds__(256) void count_deg_k(const int* __restrict__ dst,
                                                   int* __restrict__ deg, int E) {
    int e = blockIdx.x * 256 + threadIdx.x;
    if (e < E) atomicAdd(&deg[dst[e]], 1);
}

__global__ __launch_bounds__(256) void dinv_k(const int* __restrict__ deg,
                                              float* __restrict__ dinv) {
    int v = blockIdx.x * 256 + threadIdx.x;
    if (v < N_NODES) dinv[v] = rsqrtf((float)deg[v] + 1.0f);  // +1 = self-loop
}

// ============ CSR build: offsets = exclusive scan of (deg+1) ============

__global__ __launch_bounds__(256) void blocksum_k(const int* __restrict__ deg,
                                                  int* __restrict__ blockSums) {
    __shared__ int sd[256];
    int v = blockIdx.x * 256 + threadIdx.x;
    sd[threadIdx.x] = (v < N_NODES) ? deg[v] + 1 : 0;
    __syncthreads();
    for (int s = 128; s > 0; s >>= 1) {
        if (threadIdx.x < s) sd[threadIdx.x] += sd[threadIdx.x + s];
        __syncthreads();
    }
    if (threadIdx.x == 0) blockSums[blockIdx.x] = sd[0];
}

__global__ __launch_bounds__(256) void scanblocks_k(const int* __restrict__ blockSums,
                                                    int* __restrict__ blockOffs, int nb) {
    __shared__ int ps[256];
    int t = threadIdx.x;
    int a = (2 * t < nb) ? blockSums[2 * t] : 0;
    int b = (2 * t + 1 < nb) ? blockSums[2 * t + 1] : 0;
    ps[t] = a + b;
    __syncthreads();
    for (int off = 1; off < 256; off <<= 1) {
        int val = ps[t];
        int add = (t >= off) ? ps[t - off] : 0;
        __syncthreads();
        ps[t] = val + add;
        __syncthreads();
    }
    int excl = ps[t] - (a + b);
    if (2 * t < nb)     blockOffs[2 * t]     = excl;
    if (2 * t + 1 < nb) blockOffs[2 * t + 1] = excl + a;
}

__global__ __launch_bounds__(256) void offsets_k(const int* __restrict__ deg,
        const int* __restrict__ blockOffs, int* __restrict__ offsets) {
    __shared__ int ps[256];
    int t = threadIdx.x;
    int v = blockIdx.x * 256 + t;
    int d = (v < N_NODES) ? deg[v] + 1 : 0;
    ps[t] = d;
    __syncthreads();
    for (int off = 1; off < 256; off <<= 1) {
        int val = ps[t];
        int add = (t >= off) ? ps[t - off] : 0;
        __syncthreads();
        ps[t] = val + add;
        __syncthreads();
    }
    int incl = ps[t];
    int base = blockOffs[blockIdx.x];
    if (v < N_NODES) offsets[v] = base + incl - d;
    if (v == N_NODES - 1) offsets[N_NODES] = base + incl;
}

__global__ __launch_bounds__(256) void fill_k(const int* __restrict__ src,
        const int* __restrict__ dst, const int* __restrict__ offsets,
        int* __restrict__ cursor, int* __restrict__ srt_src, int E) {
    int e = blockIdx.x * 256 + threadIdx.x;
    if (e >= E + N_NODES) return;
    int s, d;
    if (e < E) { s = src[e]; d = dst[e]; }
    else       { s = d = e - E; }
    int pos = atomicAdd(&cursor[d], 1);
    srt_src[offsets[d] + pos] = s;
}

// ============ GEMM1: h1b[N,64](bf16) = dinv[row] * (x[N,128] @ W1) ============

__global__ __launch_bounds__(256) void gemm1_k(const float* __restrict__ x,
                                               const float* __restrict__ W1,
                                               const float* __restrict__ dinv,
                                               u16* __restrict__ h1b) {
    __shared__ float Ws[128 * 64];
    for (int i = threadIdx.x; i < 128 * 64; i += 256) Ws[i] = W1[i];
    __syncthreads();
    int lane = threadIdx.x & 63;
    int base = (blockIdx.x * 4 + (threadIdx.x >> 6)) * 8;
    for (int rr = 0; rr < 8; ++rr) {
        int row = __builtin_amdgcn_readfirstlane(base + rr);
        const float* xr = x + row * 128;
        float acc = 0.f;
#pragma unroll
        for (int k = 0; k < 128; ++k)
            acc = fmaf(xr[k], Ws[k * 64 + lane], acc);
        h1b[row * 64 + lane] = f2bf(dinv[row] * acc);
    }
}

// ============ layer2: h2b = dinv[v] * (relu(dinv[v]*agg + b1) @ W2) ============
// one wave per node; quarter-wave per edge (uint2 = 8B/lane covers the 128B
// row); 2x unroll -> 8 edges in flight; pure gather+add inner loop.

__global__ __launch_bounds__(256) void layer2_k(const int* __restrict__ offsets,
        const int* __restrict__ srt_src, const float* __restrict__ dinv,
        const u16* __restrict__ h1b, const float* __restrict__ b1,
        const float* __restrict__ W2, u16* __restrict__ h2b) {
    __shared__ float W2s[64 * 32];
    __shared__ float b1s[64];
    for (int i = threadIdx.x; i < 64 * 32; i += 256) W2s[i] = W2[i];
    if (threadIdx.x < 64) b1s[threadIdx.x] = b1[threadIdx.x];
    __syncthreads();
    int lane = threadIdx.x & 63;
    int f = lane & 15, q = lane >> 4;
    int v = blockIdx.x * 4 + (threadIdx.x >> 6);   // grid = N/4 exactly
    int beg = offsets[v], end = offsets[v + 1];
    const uint2* rows = (const uint2*)h1b;         // row s = rows + s*16
    float a0 = 0.f, a1 = 0.f, a2 = 0.f, a3 = 0.f;
    int i = beg;
    for (; i + 8 <= end; i += 8) {
        int s0 = srt_src[i + q];
        int s1 = srt_src[i + 4 + q];
        uint2 p0 = rows[s0 * 16 + f];
        uint2 p1 = rows[s1 * 16 + f];
        acc2(p0.x, a0, a1); acc2(p0.y, a2, a3);
        acc2(p1.x, a0, a1); acc2(p1.y, a2, a3);
    }
    for (; i < end; i += 4) {
        int j = i + q;
        if (j < end) {
            int s = srt_src[j];
            uint2 p = rows[s * 16 + f];
            acc2(p.x, a0, a1); acc2(p.y, a2, a3);
        }
    }
    a0 += __shfl_xor(a0, 16, 64); a0 += __shfl_xor(a0, 32, 64);
    a1 += __shfl_xor(a1, 16, 64); a1 += __shfl_xor(a1, 32, 64);
    a2 += __shfl_xor(a2, 16, 64); a2 += __shfl_xor(a2, 32, 64);
    a3 += __shfl_xor(a3, 16, 64); a3 += __shfl_xor(a3, 32, 64);
    // lane (f-class) now holds agg feats 4f..4f+3 (pre-dinv[v])
    float dv = dinv[v];
    float r0 = fmaxf(fmaf(dv, a0, b1s[4 * f + 0]), 0.f);
    float r1 = fmaxf(fmaf(dv, a1, b1s[4 * f + 1]), 0.f);
    float r2 = fmaxf(fmaf(dv, a2, b1s[4 * f + 2]), 0.f);
    float r3 = fmaxf(fmaf(dv, a3, b1s[4 * f + 3]), 0.f);
    int c = lane & 31;
    float o = 0.f;
#pragma unroll
    for (int j2 = 0; j2 < 16; ++j2) {
        float R0 = __shfl(r0, j2, 16);
        float R1 = __shfl(r1, j2, 16);
        float R2 = __shfl(r2, j2, 16);
        float R3 = __shfl(r3, j2, 16);
        o = fmaf(R0, W2s[(4 * j2 + 0) * 32 + c], o);
        o = fmaf(R1, W2s[(4 * j2 + 1) * 32 + c], o);
        o = fmaf(R2, W2s[(4 * j2 + 2) * 32 + c], o);
        o = fmaf(R3, W2s[(4 * j2 + 3) * 32 + c], o);
    }
    if (lane < 32) h2b[v * 32 + c] = f2bf(dv * o);
}

// ============ layer3: out = relu(dinv[v]*agg(h2b) + b2) @ Wfc + bfc ============
// one wave per node; octet per edge (uint2 = 8B/lane covers the 64B row);
// 2x unroll -> 16 edges in flight.

__global__ __launch_bounds__(256) void layer3_k(const int* __restrict__ offsets,
        const int* __restrict__ srt_src, const float* __restrict__ dinv,
        const u16* __restrict__ h2b, const float* __restrict__ b2,
        const float* __restrict__ Wfc, const float* __restrict__ bfc,
        float* __restrict__ out) {
    int lane = threadIdx.x & 63;
    int f = lane & 7, oc = lane >> 3;
    int v = blockIdx.x * 4 + (threadIdx.x >> 6);   // grid = N/4 exactly
    int beg = offsets[v], end = offsets[v + 1];
    const uint2* rows = (const uint2*)h2b;         // row s = rows + s*8
    float a0 = 0.f, a1 = 0.f, a2 = 0.f, a3 = 0.f;
    int i = beg;
    for (; i + 16 <= end; i += 16) {
        int s0 = srt_src[i + oc];
        int s1 = srt_src[i + 8 + oc];
        uint2 p0 = rows[s0 * 8 + f];
        uint2 p1 = rows[s1 * 8 + f];
        acc2(p0.x, a0, a1); acc2(p0.y, a2, a3);
        acc2(p1.x, a0, a1); acc2(p1.y, a2, a3);
    }
    for (; i < end; i += 8) {
        int j = i + oc;
        if (j < end) {
            int s = srt_src[j];
            uint2 p = rows[s * 8 + f];
            acc2(p.x, a0, a1); acc2(p.y, a2, a3);
        }
    }
    a0 += __shfl_xor(a0, 8, 64); a0 += __shfl_xor(a0, 16, 64); a0 += __shfl_xor(a0, 32, 64);
    a1 += __shfl_xor(a1, 8, 64); a1 += __shfl_xor(a1, 16, 64); a1 += __shfl_xor(a1, 32, 64);
    a2 += __shfl_xor(a2, 8, 64); a2 += __shfl_xor(a2, 16, 64); a2 += __shfl_xor(a2, 32, 64);
    a3 += __shfl_xor(a3, 8, 64); a3 += __shfl_xor(a3, 16, 64); a3 += __shfl_xor(a3, 32, 64);
    float dv = dinv[v];
    float pr = fmaxf(fmaf(dv, a0, b2[4 * f + 0]), 0.f) * Wfc[4 * f + 0]
             + fmaxf(fmaf(dv, a1, b2[4 * f + 1]), 0.f) * Wfc[4 * f + 1]
             + fmaxf(fmaf(dv, a2, b2[4 * f + 2]), 0.f) * Wfc[4 * f + 2]
             + fmaxf(fmaf(dv, a3, b2[4 * f + 3]), 0.f) * Wfc[4 * f + 3];
    pr += __shfl_xor(pr, 1, 64);
    pr += __shfl_xor(pr, 2, 64);
    pr += __shfl_xor(pr, 4, 64);
    if (lane == 0) out[v] = pr + bfc[0];
}

// ============ launch ============

extern "C" void kernel_launch(void* const* d_in, const int* in_sizes, int n_in,
                              void* d_out, int out_size, void* d_ws, size_t ws_size,
                              hipStream_t stream) {
    const float* x   = (const float*)d_in[0];
    const int*   ei  = (const int*)d_in[1];
    const float* W1  = (const float*)d_in[2];
    const float* b1  = (const float*)d_in[3];
    const float* W2  = (const float*)d_in[4];
    const float* b2  = (const float*)d_in[5];
    const float* Wfc = (const float*)d_in[6];
    const float* bfc = (const float*)d_in[7];
    float* out = (float*)d_out;

    const int E = in_sizes[1] / 2;
    const int* src = ei;
    const int* dst = ei + E;
    const int NB = (N_NODES + 255) / 256;

    int*   deg       = (int*)d_ws;                 // N
    int*   cursor    = deg + N_NODES;              // N
    int*   offsets   = cursor + N_NODES;           // N+1
    int*   blockSums = offsets + N_NODES + 1;      // 512
    int*   blockOffs = blockSums + 512;            // 512
    int*   srt_src   = blockOffs + 512;            // E+N
    float* dinv      = (float*)(srt_src + E + N_NODES);  // N
    u16*   h1b       = (u16*)(dinv + N_NODES);     // N*64 bf16
    u16*   h2b       = h1b + (size_t)N_NODES * 64; // N*32 bf16

    hipMemsetAsync(deg, 0, 2 * N_NODES * sizeof(int), stream);  // deg + cursor
    count_deg_k<<<(E + 255) / 256, 256, 0, stream>>>(dst, deg, E);
    dinv_k<<<NB, 256, 0, stream>>>(deg, dinv);
    blocksum_k<<<NB, 256, 0, stream>>>(deg, blockSums);
    scanblocks_k<<<1, 256, 0, stream>>>(blockSums, blockOffs, NB);
    offsets_k<<<NB, 256, 0, stream>>>(deg, blockOffs, offsets);
    fill_k<<<(E + N_NODES + 255) / 256, 256, 0, stream>>>(src, dst, offsets, cursor,
                                                          srt_src, E);

    gemm1_k<<<N_NODES / 32, 256, 0, stream>>>(x, W1, dinv, h1b);

    layer2_k<<<N_NODES / 4, 256, 0, stream>>>(offsets, srt_src, dinv, h1b, b1, W2, h2b);
    layer3_k<<<N_NODES / 4, 256, 0, stream>>>(offsets, srt_src, dinv, h2b, b2, Wfc,
                                              bfc, out);
}

// Round 5
// 377.573 us; speedup vs baseline: 1.9261x; 1.1468x over previous
//
#include <hip/hip_runtime.h>

#define N_NODES 100000
typedef unsigned int u32;
typedef unsigned short u16;

static __device__ __forceinline__ u16 f2bf(float f) {  // round-nearest-even
    union { float f; u32 u; } c; c.f = f;
    u32 r = (c.u + 0x7fffu + ((c.u >> 16) & 1u)) >> 16;
    return (u16)r;
}
// accumulate a packed pair of bf16 into two f32 accumulators
static __device__ __forceinline__ void acc2(u32 p, float& a, float& b) {
    union { u32 u; float f; } lo, hi;
    lo.u = p << 16;
    hi.u = p & 0xffff0000u;
    a += lo.f;
    b += hi.f;
}

// ============ degree ============

__global__ __launch_bounds__(256) void count_deg_k(const int* __restrict__ dst,
                                                   int* __restrict__ deg, int E) {
    int e = blockIdx.x * 256 + threadIdx.x;
    if (e < E) atomicAdd(&deg[dst[e]], 1);
}

// ============ CSR build: offsets = exclusive scan of (deg+1); also dinv ======

__global__ __launch_bounds__(256) void blocksum_k(const int* __restrict__ deg,
                                                  float* __restrict__ dinv,
                                                  int* __restrict__ blockSums) {
    __shared__ int sd[256];
    int v = blockIdx.x * 256 + threadIdx.x;
    int d = (v < N_NODES) ? deg[v] + 1 : 0;
    if (v < N_NODES) dinv[v] = rsqrtf((float)d);
    sd[threadIdx.x] = d;
    __syncthreads();
    for (int s = 128; s > 0; s >>= 1) {
        if (threadIdx.x < s) sd[threadIdx.x] += sd[threadIdx.x + s];
        __syncthreads();
    }
    if (threadIdx.x == 0) blockSums[blockIdx.x] = sd[0];
}

__global__ __launch_bounds__(256) void scanblocks_k(const int* __restrict__ blockSums,
                                                    int* __restrict__ blockOffs, int nb) {
    __shared__ int ps[256];
    int t = threadIdx.x;
    int a = (2 * t < nb) ? blockSums[2 * t] : 0;
    int b = (2 * t + 1 < nb) ? blockSums[2 * t + 1] : 0;
    ps[t] = a + b;
    __syncthreads();
    for (int off = 1; off < 256; off <<= 1) {
        int val = ps[t];
        int add = (t >= off) ? ps[t - off] : 0;
        __syncthreads();
        ps[t] = val + add;
        __syncthreads();
    }
    int excl = ps[t] - (a + b);
    if (2 * t < nb)     blockOffs[2 * t]     = excl;
    if (2 * t + 1 < nb) blockOffs[2 * t + 1] = excl + a;
}

__global__ __launch_bounds__(256) void offsets_k(const int* __restrict__ deg,
        const int* __restrict__ blockOffs, int* __restrict__ offsets) {
    __shared__ int ps[256];
    int t = threadIdx.x;
    int v = blockIdx.x * 256 + t;
    int d = (v < N_NODES) ? deg[v] + 1 : 0;
    ps[t] = d;
    __syncthreads();
    for (int off = 1; off < 256; off <<= 1) {
        int val = ps[t];
        int add = (t >= off) ? ps[t - off] : 0;
        __syncthreads();
        ps[t] = val + add;
        __syncthreads();
    }
    int incl = ps[t];
    int base = blockOffs[blockIdx.x];
    if (v < N_NODES) offsets[v] = base + incl - d;
    if (v == N_NODES - 1) offsets[N_NODES] = base + incl;
}

__global__ __launch_bounds__(256) void fill_k(const int* __restrict__ src,
        const int* __restrict__ dst, const int* __restrict__ offsets,
        int* __restrict__ cursor, int* __restrict__ srt_src, int E) {
    int e = blockIdx.x * 256 + threadIdx.x;
    if (e >= E + N_NODES) return;
    int s, d;
    if (e < E) { s = src[e]; d = dst[e]; }
    else       { s = d = e - E; }
    int pos = atomicAdd(&cursor[d], 1);
    srt_src[offsets[d] + pos] = s;
}

// ============ GEMM1: h1b[N,64](bf16) = dinv[row] * (x[N,128] @ W1) ============

__global__ __launch_bounds__(256) void gemm1_k(const float* __restrict__ x,
                                               const float* __restrict__ W1,
                                               const float* __restrict__ dinv,
                                               u16* __restrict__ h1b) {
    __shared__ float Ws[128 * 64];
    for (int i = threadIdx.x; i < 128 * 64; i += 256) Ws[i] = W1[i];
    __syncthreads();
    int lane = threadIdx.x & 63;
    int base = (blockIdx.x * 4 + (threadIdx.x >> 6)) * 8;
    for (int rr = 0; rr < 8; ++rr) {
        int row = __builtin_amdgcn_readfirstlane(base + rr);
        const float* xr = x + row * 128;
        float acc = 0.f;
#pragma unroll
        for (int k = 0; k < 128; ++k)
            acc = fmaf(xr[k], Ws[k * 64 + lane], acc);
        h1b[row * 64 + lane] = f2bf(dinv[row] * acc);
    }
}

// ============ layer2: h2b = dinv * (relu(dinv*agg + b1) @ W2) ============
// 2 nodes per wave (contiguous CSR ranges); quarter-wave per edge (uint2);
// main loop keeps 4 independent gathers (16 edges) in flight.

__global__ __launch_bounds__(256) void layer2_k(const int* __restrict__ offsets,
        const int* __restrict__ srt_src, const float* __restrict__ dinv,
        const u16* __restrict__ h1b, const float* __restrict__ b1,
        const float* __restrict__ W2, u16* __restrict__ h2b) {
    __shared__ float W2s[64 * 32];
    __shared__ float b1s[64];
    for (int i = threadIdx.x; i < 64 * 32; i += 256) W2s[i] = W2[i];
    if (threadIdx.x < 64) b1s[threadIdx.x] = b1[threadIdx.x];
    __syncthreads();
    int lane = threadIdx.x & 63;
    int f = lane & 15, q = lane >> 4;
    int v0 = blockIdx.x * 8 + (threadIdx.x >> 6) * 2;   // grid = N/8
    int v1 = v0 + 1;
    int i0 = offsets[v0], e0 = offsets[v1], e1 = offsets[v1 + 1];
    int i1 = e0;
    const uint2* rows = (const uint2*)h1b;              // row s = rows + s*16
    float a0 = 0.f, a1 = 0.f, a2 = 0.f, a3 = 0.f;       // node0
    float c0 = 0.f, c1 = 0.f, c2 = 0.f, c3 = 0.f;       // node1
    // main: 8 edges per node per iter, 4 gathers in flight
    while (i0 + 8 <= e0 && i1 + 8 <= e1) {
        int sA = srt_src[i0 + q];
        int sB = srt_src[i0 + 4 + q];
        int sC = srt_src[i1 + q];
        int sD = srt_src[i1 + 4 + q];
        uint2 pA = rows[sA * 16 + f];
        uint2 pB = rows[sB * 16 + f];
        uint2 pC = rows[sC * 16 + f];
        uint2 pD = rows[sD * 16 + f];
        acc2(pA.x, a0, a1); acc2(pA.y, a2, a3);
        acc2(pB.x, a0, a1); acc2(pB.y, a2, a3);
        acc2(pC.x, c0, c1); acc2(pC.y, c2, c3);
        acc2(pD.x, c0, c1); acc2(pD.y, c2, c3);
        i0 += 8; i1 += 8;
    }
    // drain node0
    for (; i0 + 8 <= e0; i0 += 8) {
        int sA = srt_src[i0 + q], sB = srt_src[i0 + 4 + q];
        uint2 pA = rows[sA * 16 + f], pB = rows[sB * 16 + f];
        acc2(pA.x, a0, a1); acc2(pA.y, a2, a3);
        acc2(pB.x, a0, a1); acc2(pB.y, a2, a3);
    }
    for (; i0 < e0; i0 += 4) {
        int j = i0 + q;
        if (j < e0) {
            int s = srt_src[j];
            uint2 p = rows[s * 16 + f];
            acc2(p.x, a0, a1); acc2(p.y, a2, a3);
        }
    }
    // drain node1
    for (; i1 + 8 <= e1; i1 += 8) {
        int sA = srt_src[i1 + q], sB = srt_src[i1 + 4 + q];
        uint2 pA = rows[sA * 16 + f], pB = rows[sB * 16 + f];
        acc2(pA.x, c0, c1); acc2(pA.y, c2, c3);
        acc2(pB.x, c0, c1); acc2(pB.y, c2, c3);
    }
    for (; i1 < e1; i1 += 4) {
        int j = i1 + q;
        if (j < e1) {
            int s = srt_src[j];
            uint2 p = rows[s * 16 + f];
            acc2(p.x, c0, c1); acc2(p.y, c2, c3);
        }
    }
    // reduce across quarters -> every lane holds both nodes' agg (feats 4f..4f+3)
    a0 += __shfl_xor(a0, 16, 64); a0 += __shfl_xor(a0, 32, 64);
    a1 += __shfl_xor(a1, 16, 64); a1 += __shfl_xor(a1, 32, 64);
    a2 += __shfl_xor(a2, 16, 64); a2 += __shfl_xor(a2, 32, 64);
    a3 += __shfl_xor(a3, 16, 64); a3 += __shfl_xor(a3, 32, 64);
    c0 += __shfl_xor(c0, 16, 64); c0 += __shfl_xor(c0, 32, 64);
    c1 += __shfl_xor(c1, 16, 64); c1 += __shfl_xor(c1, 32, 64);
    c2 += __shfl_xor(c2, 16, 64); c2 += __shfl_xor(c2, 32, 64);
    c3 += __shfl_xor(c3, 16, 64); c3 += __shfl_xor(c3, 32, 64);
    // lanes 0-31 own node0, lanes 32-63 own node1
    bool lo = (lane < 32);
    float dv = lo ? dinv[v0] : dinv[v1];
    float t0 = lo ? a0 : c0;
    float t1 = lo ? a1 : c1;
    float t2 = lo ? a2 : c2;
    float t3 = lo ? a3 : c3;
    float r0 = fmaxf(fmaf(dv, t0, b1s[4 * f + 0]), 0.f);
    float r1 = fmaxf(fmaf(dv, t1, b1s[4 * f + 1]), 0.f);
    float r2 = fmaxf(fmaf(dv, t2, b1s[4 * f + 2]), 0.f);
    float r3 = fmaxf(fmaf(dv, t3, b1s[4 * f + 3]), 0.f);
    int c = lane & 31;
    float o = 0.f;
#pragma unroll
    for (int j2 = 0; j2 < 16; ++j2) {
        float R0 = __shfl(r0, j2, 16);
        float R1 = __shfl(r1, j2, 16);
        float R2 = __shfl(r2, j2, 16);
        float R3 = __shfl(r3, j2, 16);
        o = fmaf(R0, W2s[(4 * j2 + 0) * 32 + c], o);
        o = fmaf(R1, W2s[(4 * j2 + 1) * 32 + c], o);
        o = fmaf(R2, W2s[(4 * j2 + 2) * 32 + c], o);
        o = fmaf(R3, W2s[(4 * j2 + 3) * 32 + c], o);
    }
    int vst = lo ? v0 : v1;
    h2b[vst * 32 + c] = f2bf(dv * o);
}

// ============ layer3: out = relu(dinv*agg(h2b) + b2) @ Wfc + bfc ============
// 4 nodes per wave; octet per edge (uint2 covers the 64B row); main loop
// keeps 4 independent gathers (32 edges) in flight.

#define GATH3(ii, A, B, C, D) { \
    int s_ = srt_src[(ii) + oc]; \
    uint2 p_ = rows[s_ * 8 + f]; \
    acc2(p_.x, A, B); acc2(p_.y, C, D); }

__global__ __launch_bounds__(256) void layer3_k(const int* __restrict__ offsets,
        const int* __restrict__ srt_src, const float* __restrict__ dinv,
        const u16* __restrict__ h2b, const float* __restrict__ b2,
        const float* __restrict__ Wfc, const float* __restrict__ bfc,
        float* __restrict__ out) {
    int lane = threadIdx.x & 63;
    int f = lane & 7, oc = lane >> 3;
    int vb = blockIdx.x * 16 + (threadIdx.x >> 6) * 4;   // grid = N/16
    int o0 = offsets[vb], o1 = offsets[vb + 1], o2 = offsets[vb + 2];
    int o3 = offsets[vb + 3], o4 = offsets[vb + 4];
    int i0 = o0, e0 = o1, i1 = o1, e1 = o2, i2 = o2, e2 = o3, i3 = o3, e3 = o4;
    const uint2* rows = (const uint2*)h2b;               // row s = rows + s*8
    float A0=0.f,A1=0.f,A2=0.f,A3=0.f, B0=0.f,B1=0.f,B2=0.f,B3=0.f;
    float C0=0.f,C1=0.f,C2=0.f,C3=0.f, D0=0.f,D1=0.f,D2=0.f,D3=0.f;
    while (i0 + 8 <= e0 && i1 + 8 <= e1 && i2 + 8 <= e2 && i3 + 8 <= e3) {
        GATH3(i0, A0, A1, A2, A3);
        GATH3(i1, B0, B1, B2, B3);
        GATH3(i2, C0, C1, C2, C3);
        GATH3(i3, D0, D1, D2, D3);
        i0 += 8; i1 += 8; i2 += 8; i3 += 8;
    }
    while (i0 + 8 <= e0) { GATH3(i0, A0, A1, A2, A3); i0 += 8; }
    if (i0 + oc < e0)    { GATH3(i0, A0, A1, A2, A3); }
    while (i1 + 8 <= e1) { GATH3(i1, B0, B1, B2, B3); i1 += 8; }
    if (i1 + oc < e1)    { GATH3(i1, B0, B1, B2, B3); }
    while (i2 + 8 <= e2) { GATH3(i2, C0, C1, C2, C3); i2 += 8; }
    if (i2 + oc < e2)    { GATH3(i2, C0, C1, C2, C3); }
    while (i3 + 8 <= e3) { GATH3(i3, D0, D1, D2, D3); i3 += 8; }
    if (i3 + oc < e3)    { GATH3(i3, D0, D1, D2, D3); }
#define RED3(X) X += __shfl_xor(X, 8, 64); X += __shfl_xor(X, 16, 64); X += __shfl_xor(X, 32, 64)
    RED3(A0); RED3(A1); RED3(A2); RED3(A3);
    RED3(B0); RED3(B1); RED3(B2); RED3(B3);
    RED3(C0); RED3(C1); RED3(C2); RED3(C3);
    RED3(D0); RED3(D1); RED3(D2); RED3(D3);
    float w0 = Wfc[4 * f + 0], w1 = Wfc[4 * f + 1];
    float w2 = Wfc[4 * f + 2], w3 = Wfc[4 * f + 3];
    float g0 = b2[4 * f + 0], g1 = b2[4 * f + 1];
    float g2 = b2[4 * f + 2], g3 = b2[4 * f + 3];
    float dv0 = dinv[vb], dv1 = dinv[vb + 1], dv2 = dinv[vb + 2], dv3 = dinv[vb + 3];
    float p0 = fmaxf(fmaf(dv0, A0, g0), 0.f) * w0 + fmaxf(fmaf(dv0, A1, g1), 0.f) * w1
             + fmaxf(fmaf(dv0, A2, g2), 0.f) * w2 + fmaxf(fmaf(dv0, A3, g3), 0.f) * w3;
    float p1 = fmaxf(fmaf(dv1, B0, g0), 0.f) * w0 + fmaxf(fmaf(dv1, B1, g1), 0.f) * w1
             + fmaxf(fmaf(dv1, B2, g2), 0.f) * w2 + fmaxf(fmaf(dv1, B3, g3), 0.f) * w3;
    float p2 = fmaxf(fmaf(dv2, C0, g0), 0.f) * w0 + fmaxf(fmaf(dv2, C1, g1), 0.f) * w1
             + fmaxf(fmaf(dv2, C2, g2), 0.f) * w2 + fmaxf(fmaf(dv2, C3, g3), 0.f) * w3;
    float p3 = fmaxf(fmaf(dv3, D0, g0), 0.f) * w0 + fmaxf(fmaf(dv3, D1, g1), 0.f) * w1
             + fmaxf(fmaf(dv3, D2, g2), 0.f) * w2 + fmaxf(fmaf(dv3, D3, g3), 0.f) * w3;
#define REDP(X) X += __shfl_xor(X, 1, 64); X += __shfl_xor(X, 2, 64); X += __shfl_xor(X, 4, 64)
    REDP(p0); REDP(p1); REDP(p2); REDP(p3);
    if (lane == 0) {
        float bb = bfc[0];
        out[vb + 0] = p0 + bb;
        out[vb + 1] = p1 + bb;
        out[vb + 2] = p2 + bb;
        out[vb + 3] = p3 + bb;
    }
}

// ============ launch ============

extern "C" void kernel_launch(void* const* d_in, const int* in_sizes, int n_in,
                              void* d_out, int out_size, void* d_ws, size_t ws_size,
                              hipStream_t stream) {
    const float* x   = (const float*)d_in[0];
    const int*   ei  = (const int*)d_in[1];
    const float* W1  = (const float*)d_in[2];
    const float* b1  = (const float*)d_in[3];
    const float* W2  = (const float*)d_in[4];
    const float* b2  = (const float*)d_in[5];
    const float* Wfc = (const float*)d_in[6];
    const float* bfc = (const float*)d_in[7];
    float* out = (float*)d_out;

    const int E = in_sizes[1] / 2;
    const int* src = ei;
    const int* dst = ei + E;
    const int NB = (N_NODES + 255) / 256;

    int*   deg       = (int*)d_ws;                 // N
    int*   cursor    = deg + N_NODES;              // N
    int*   offsets   = cursor + N_NODES;           // N+1
    int*   blockSums = offsets + N_NODES + 1;      // 512
    int*   blockOffs = blockSums + 512;            // 512
    int*   srt_src   = blockOffs + 512;            // E+N
    float* dinv      = (float*)(srt_src + E + N_NODES);  // N
    u16*   h1b       = (u16*)(dinv + N_NODES);     // N*64 bf16
    u16*   h2b       = h1b + (size_t)N_NODES * 64; // N*32 bf16

    hipMemsetAsync(deg, 0, 2 * N_NODES * sizeof(int), stream);  // deg + cursor
    count_deg_k<<<(E + 255) / 256, 256, 0, stream>>>(dst, deg, E);
    blocksum_k<<<NB, 256, 0, stream>>>(deg, dinv, blockSums);
    scanblocks_k<<<1, 256, 0, stream>>>(blockSums, blockOffs, NB);
    offsets_k<<<NB, 256, 0, stream>>>(deg, blockOffs, offsets);
    fill_k<<<(E + N_NODES + 255) / 256, 256, 0, stream>>>(src, dst, offsets, cursor,
                                                          srt_src, E);

    gemm1_k<<<N_NODES / 32, 256, 0, stream>>>(x, W1, dinv, h1b);

    layer2_k<<<N_NODES / 8, 256, 0, stream>>>(offsets, srt_src, dinv, h1b, b1, W2, h2b);
    layer3_k<<<N_NODES / 16, 256, 0, stream>>>(offsets, srt_src, dinv, h2b, b2, Wfc,
                                               bfc, out);
}

// Round 6
// 259.743 us; speedup vs baseline: 2.7998x; 1.4536x over previous
//
#include <hip/hip_runtime.h>

#define N_NODES 100000
#define BSH 9                      // 512 nodes per bucket
#define NBKT ((N_NODES + 511) >> BSH)   // 196
#define CH 7168                    // items per partition chunk (56KB LDS stage)

typedef unsigned int u32;
typedef unsigned short u16;

static __device__ __forceinline__ u16 f2bf(float f) {  // round-nearest-even
    union { float f; u32 u; } c; c.f = f;
    u32 r = (c.u + 0x7fffu + ((c.u >> 16) & 1u)) >> 16;
    return (u16)r;
}
static __device__ __forceinline__ void acc2(u32 p, float& a, float& b) {
    union { u32 u; float f; } lo, hi;
    lo.u = p << 16;
    hi.u = p & 0xffff0000u;
    a += lo.f;
    b += hi.f;
}

// ============ CSR build, bucketed ============
// item e in [0,E) = edge (src[e],dst[e]); e in [E,E+N) = self-loop (v,v).

__global__ __launch_bounds__(256) void coarsehist_k(const int* __restrict__ dst,
        int* __restrict__ ccount, int E, int TOT) {
    __shared__ int hist[256];
    hist[threadIdx.x] = 0;
    __syncthreads();
    int base = blockIdx.x * CH;
    int cnt = min(CH, TOT - base);
    for (int i = threadIdx.x; i < cnt; i += 256) {
        int e = base + i;
        int d = (e < E) ? dst[e] : e - E;
        atomicAdd(&hist[d >> BSH], 1);
    }
    __syncthreads();
    if (hist[threadIdx.x]) atomicAdd(&ccount[threadIdx.x], hist[threadIdx.x]);
}

// single block: scan 196 coarse counts -> cbase[0..NBKT], bcur, offsets[N]
__global__ __launch_bounds__(256) void coarsescan_k(const int* __restrict__ ccount,
        int* __restrict__ cbase, int* __restrict__ bcur, int* __restrict__ offsets) {
    __shared__ int ps[256];
    int t = threadIdx.x;
    int c = (t < NBKT) ? ccount[t] : 0;
    ps[t] = c;
    __syncthreads();
    for (int off = 1; off < 256; off <<= 1) {
        int val = ps[t];
        int add = (t >= off) ? ps[t - off] : 0;
        __syncthreads();
        ps[t] = val + add;
        __syncthreads();
    }
    int incl = ps[t], excl = incl - c;
    if (t < NBKT) cbase[t] = excl;
    bcur[t] = (t < NBKT) ? excl : incl;   // t>=NBKT: total (unused)
    if (t == NBKT - 1) cbase[NBKT] = incl;
    if (t == 255) offsets[N_NODES] = ps[255];
}

// chunked LDS counting-sort partition: items -> bktBuf grouped by bucket,
// each (block,bucket) run written contiguously (line-efficient, single-XCD).
__global__ __launch_bounds__(256) void partition_k(const int* __restrict__ src,
        const int* __restrict__ dst, int* __restrict__ bcur,
        uint2* __restrict__ bktBuf, int E, int TOT) {
    __shared__ int hist[256];
    __shared__ int lbase[256];
    __shared__ int gbase[256];
    __shared__ int ps[256];
    __shared__ uint2 stage[CH];
    int t = threadIdx.x;
    int base = blockIdx.x * CH;
    int cnt = min(CH, TOT - base);
    hist[t] = 0;
    __syncthreads();
    // pass A: bucket counts
    for (int i = t; i < cnt; i += 256) {
        int e = base + i;
        int d = (e < E) ? dst[e] : e - E;
        atomicAdd(&hist[d >> BSH], 1);
    }
    __syncthreads();
    // scan -> local bases; reserve global runs
    ps[t] = hist[t];
    __syncthreads();
    for (int off = 1; off < 256; off <<= 1) {
        int val = ps[t];
        int add = (t >= off) ? ps[t - off] : 0;
        __syncthreads();
        ps[t] = val + add;
        __syncthreads();
    }
    lbase[t] = ps[t] - hist[t];
    gbase[t] = atomicAdd(&bcur[t], hist[t]);
    hist[t] = 0;                 // reuse as local cursor
    __syncthreads();
    // pass B: stage bucket-sorted in LDS
    for (int i = t; i < cnt; i += 256) {
        int e = base + i;
        int s, d;
        if (e < E) { s = src[e]; d = dst[e]; }
        else       { s = d = e - E; }
        int b = d >> BSH;
        int lpos = lbase[b] + atomicAdd(&hist[b], 1);
        stage[lpos] = make_uint2((u32)s, (u32)d);
    }
    __syncthreads();
    // pass C: contiguous run writes
    for (int i = t; i < cnt; i += 256) {
        uint2 p = stage[i];
        int b = (int)p.y >> BSH;
        bktBuf[gbase[b] + (i - lbase[b])] = p;
    }
}

// one block per bucket: local deg histogram+scan -> offsets, dinv; then
// scatter srt_src inside the block-exclusive window.
__global__ __launch_bounds__(256) void buildfill_k(const int* __restrict__ cbase,
        const uint2* __restrict__ bktBuf, int* __restrict__ offsets,
        float* __restrict__ dinv, int* __restrict__ srt_src) {
    __shared__ int hist[512];
    __shared__ int hscan[512];
    __shared__ int cur[512];
    __shared__ int ps[256];
    int t = threadIdx.x;
    int b = blockIdx.x;
    int v0 = b << BSH;
    int nv = min(512, N_NODES - v0);
    hist[t] = 0; hist[t + 256] = 0;
    cur[t] = 0;  cur[t + 256] = 0;
    __syncthreads();
    int beg = cbase[b], endi = cbase[b + 1];
    for (int i = beg + t; i < endi; i += 256)
        atomicAdd(&hist[(int)bktBuf[i].y - v0], 1);
    __syncthreads();
    // exclusive scan of hist[0..511] (pairs + Hillis-Steele over 256)
    int a = hist[2 * t], bb = hist[2 * t + 1];
    int own = a + bb;
    ps[t] = own;
    __syncthreads();
    for (int off = 1; off < 256; off <<= 1) {
        int val = ps[t];
        int add = (t >= off) ? ps[t - off] : 0;
        __syncthreads();
        ps[t] = val + add;
        __syncthreads();
    }
    int excl2 = ps[t] - own;
    hscan[2 * t] = excl2;
    hscan[2 * t + 1] = excl2 + a;
    __syncthreads();
    // offsets + dinv (hist includes the self-loop -> deg+1)
    for (int j = t; j < nv; j += 256) {
        offsets[v0 + j] = beg + hscan[j];
        dinv[v0 + j] = rsqrtf((float)hist[j]);
    }
    // scatter within [beg, endi) — block-exclusive window
    for (int i = beg + t; i < endi; i += 256) {
        uint2 p = bktBuf[i];
        int j = (int)p.y - v0;
        int pos = atomicAdd(&cur[j], 1);
        srt_src[beg + hscan[j] + pos] = (int)p.x;
    }
}

// ============ GEMM1: h1b[N,64](bf16) = dinv[row] * (x[N,128] @ W1) ============

__global__ __launch_bounds__(256) void gemm1_k(const float* __restrict__ x,
                                               const float* __restrict__ W1,
                                               const float* __restrict__ dinv,
                                               u16* __restrict__ h1b) {
    __shared__ float Ws[128 * 64];
    for (int i = threadIdx.x; i < 128 * 64; i += 256) Ws[i] = W1[i];
    __syncthreads();
    int lane = threadIdx.x & 63;
    int base = (blockIdx.x * 4 + (threadIdx.x >> 6)) * 8;
    for (int rr = 0; rr < 8; ++rr) {
        int row = __builtin_amdgcn_readfirstlane(base + rr);
        const float* xr = x + row * 128;
        float acc = 0.f;
#pragma unroll
        for (int k = 0; k < 128; ++k)
            acc = fmaf(xr[k], Ws[k * 64 + lane], acc);
        h1b[row * 64 + lane] = f2bf(dinv[row] * acc);
    }
}

// ============ layer2: h2b = dinv * (relu(dinv*agg + b1) @ W2) ============

__global__ __launch_bounds__(256) void layer2_k(const int* __restrict__ offsets,
        const int* __restrict__ srt_src, const float* __restrict__ dinv,
        const u16* __restrict__ h1b, const float* __restrict__ b1,
        const float* __restrict__ W2, u16* __restrict__ h2b) {
    __shared__ float W2s[64 * 32];
    __shared__ float b1s[64];
    for (int i = threadIdx.x; i < 64 * 32; i += 256) W2s[i] = W2[i];
    if (threadIdx.x < 64) b1s[threadIdx.x] = b1[threadIdx.x];
    __syncthreads();
    int lane = threadIdx.x & 63;
    int f = lane & 15, q = lane >> 4;
    int v0 = blockIdx.x * 8 + (threadIdx.x >> 6) * 2;   // grid = N/8
    int v1 = v0 + 1;
    int i0 = offsets[v0], e0 = offsets[v1], e1 = offsets[v1 + 1];
    int i1 = e0;
    const uint2* rows = (const uint2*)h1b;              // row s = rows + s*16
    float a0 = 0.f, a1 = 0.f, a2 = 0.f, a3 = 0.f;       // node0
    float c0 = 0.f, c1 = 0.f, c2 = 0.f, c3 = 0.f;       // node1
    while (i0 + 8 <= e0 && i1 + 8 <= e1) {
        int sA = srt_src[i0 + q];
        int sB = srt_src[i0 + 4 + q];
        int sC = srt_src[i1 + q];
        int sD = srt_src[i1 + 4 + q];
        uint2 pA = rows[sA * 16 + f];
        uint2 pB = rows[sB * 16 + f];
        uint2 pC = rows[sC * 16 + f];
        uint2 pD = rows[sD * 16 + f];
        acc2(pA.x, a0, a1); acc2(pA.y, a2, a3);
        acc2(pB.x, a0, a1); acc2(pB.y, a2, a3);
        acc2(pC.x, c0, c1); acc2(pC.y, c2, c3);
        acc2(pD.x, c0, c1); acc2(pD.y, c2, c3);
        i0 += 8; i1 += 8;
    }
    for (; i0 + 8 <= e0; i0 += 8) {
        int sA = srt_src[i0 + q], sB = srt_src[i0 + 4 + q];
        uint2 pA = rows[sA * 16 + f], pB = rows[sB * 16 + f];
        acc2(pA.x, a0, a1); acc2(pA.y, a2, a3);
        acc2(pB.x, a0, a1); acc2(pB.y, a2, a3);
    }
    for (; i0 < e0; i0 += 4) {
        int j = i0 + q;
        if (j < e0) {
            int s = srt_src[j];
            uint2 p = rows[s * 16 + f];
            acc2(p.x, a0, a1); acc2(p.y, a2, a3);
        }
    }
    for (; i1 + 8 <= e1; i1 += 8) {
        int sA = srt_src[i1 + q], sB = srt_src[i1 + 4 + q];
        uint2 pA = rows[sA * 16 + f], pB = rows[sB * 16 + f];
        acc2(pA.x, c0, c1); acc2(pA.y, c2, c3);
        acc2(pB.x, c0, c1); acc2(pB.y, c2, c3);
    }
    for (; i1 < e1; i1 += 4) {
        int j = i1 + q;
        if (j < e1) {
            int s = srt_src[j];
            uint2 p = rows[s * 16 + f];
            acc2(p.x, c0, c1); acc2(p.y, c2, c3);
        }
    }
    a0 += __shfl_xor(a0, 16, 64); a0 += __shfl_xor(a0, 32, 64);
    a1 += __shfl_xor(a1, 16, 64); a1 += __shfl_xor(a1, 32, 64);
    a2 += __shfl_xor(a2, 16, 64); a2 += __shfl_xor(a2, 32, 64);
    a3 += __shfl_xor(a3, 16, 64); a3 += __shfl_xor(a3, 32, 64);
    c0 += __shfl_xor(c0, 16, 64); c0 += __shfl_xor(c0, 32, 64);
    c1 += __shfl_xor(c1, 16, 64); c1 += __shfl_xor(c1, 32, 64);
    c2 += __shfl_xor(c2, 16, 64); c2 += __shfl_xor(c2, 32, 64);
    c3 += __shfl_xor(c3, 16, 64); c3 += __shfl_xor(c3, 32, 64);
    bool lo = (lane < 32);
    float dv = lo ? dinv[v0] : dinv[v1];
    float t0 = lo ? a0 : c0;
    float t1 = lo ? a1 : c1;
    float t2 = lo ? a2 : c2;
    float t3 = lo ? a3 : c3;
    float r0 = fmaxf(fmaf(dv, t0, b1s[4 * f + 0]), 0.f);
    float r1 = fmaxf(fmaf(dv, t1, b1s[4 * f + 1]), 0.f);
    float r2 = fmaxf(fmaf(dv, t2, b1s[4 * f + 2]), 0.f);
    float r3 = fmaxf(fmaf(dv, t3, b1s[4 * f + 3]), 0.f);
    int c = lane & 31;
    float o = 0.f;
#pragma unroll
    for (int j2 = 0; j2 < 16; ++j2) {
        float R0 = __shfl(r0, j2, 16);
        float R1 = __shfl(r1, j2, 16);
        float R2 = __shfl(r2, j2, 16);
        float R3 = __shfl(r3, j2, 16);
        o = fmaf(R0, W2s[(4 * j2 + 0) * 32 + c], o);
        o = fmaf(R1, W2s[(4 * j2 + 1) * 32 + c], o);
        o = fmaf(R2, W2s[(4 * j2 + 2) * 32 + c], o);
        o = fmaf(R3, W2s[(4 * j2 + 3) * 32 + c], o);
    }
    int vst = lo ? v0 : v1;
    h2b[vst * 32 + c] = f2bf(dv * o);
}

// ============ layer3: out = relu(dinv*agg(h2b) + b2) @ Wfc + bfc ============

#define GATH3(ii, A, B, C, D) { \
    int s_ = srt_src[(ii) + oc]; \
    uint2 p_ = rows[s_ * 8 + f]; \
    acc2(p_.x, A, B); acc2(p_.y, C, D); }

__global__ __launch_bounds__(256) void layer3_k(const int* __restrict__ offsets,
        const int* __restrict__ srt_src, const float* __restrict__ dinv,
        const u16* __restrict__ h2b, const float* __restrict__ b2,
        const float* __restrict__ Wfc, const float* __restrict__ bfc,
        float* __restrict__ out) {
    int lane = threadIdx.x & 63;
    int f = lane & 7, oc = lane >> 3;
    int vb = blockIdx.x * 16 + (threadIdx.x >> 6) * 4;   // grid = N/16
    int o0 = offsets[vb], o1 = offsets[vb + 1], o2 = offsets[vb + 2];
    int o3 = offsets[vb + 3], o4 = offsets[vb + 4];
    int i0 = o0, e0 = o1, i1 = o1, e1 = o2, i2 = o2, e2 = o3, i3 = o3, e3 = o4;
    const uint2* rows = (const uint2*)h2b;               // row s = rows + s*8
    float A0=0.f,A1=0.f,A2=0.f,A3=0.f, B0=0.f,B1=0.f,B2=0.f,B3=0.f;
    float C0=0.f,C1=0.f,C2=0.f,C3=0.f, D0=0.f,D1=0.f,D2=0.f,D3=0.f;
    while (i0 + 8 <= e0 && i1 + 8 <= e1 && i2 + 8 <= e2 && i3 + 8 <= e3) {
        GATH3(i0, A0, A1, A2, A3);
        GATH3(i1, B0, B1, B2, B3);
        GATH3(i2, C0, C1, C2, C3);
        GATH3(i3, D0, D1, D2, D3);
        i0 += 8; i1 += 8; i2 += 8; i3 += 8;
    }
    while (i0 + 8 <= e0) { GATH3(i0, A0, A1, A2, A3); i0 += 8; }
    if (i0 + oc < e0)    { GATH3(i0, A0, A1, A2, A3); }
    while (i1 + 8 <= e1) { GATH3(i1, B0, B1, B2, B3); i1 += 8; }
    if (i1 + oc < e1)    { GATH3(i1, B0, B1, B2, B3); }
    while (i2 + 8 <= e2) { GATH3(i2, C0, C1, C2, C3); i2 += 8; }
    if (i2 + oc < e2)    { GATH3(i2, C0, C1, C2, C3); }
    while (i3 + 8 <= e3) { GATH3(i3, D0, D1, D2, D3); i3 += 8; }
    if (i3 + oc < e3)    { GATH3(i3, D0, D1, D2, D3); }
#define RED3(X) X += __shfl_xor(X, 8, 64); X += __shfl_xor(X, 16, 64); X += __shfl_xor(X, 32, 64)
    RED3(A0); RED3(A1); RED3(A2); RED3(A3);
    RED3(B0); RED3(B1); RED3(B2); RED3(B3);
    RED3(C0); RED3(C1); RED3(C2); RED3(C3);
    RED3(D0); RED3(D1); RED3(D2); RED3(D3);
    float w0 = Wfc[4 * f + 0], w1 = Wfc[4 * f + 1];
    float w2 = Wfc[4 * f + 2], w3 = Wfc[4 * f + 3];
    float g0 = b2[4 * f + 0], g1 = b2[4 * f + 1];
    float g2 = b2[4 * f + 2], g3 = b2[4 * f + 3];
    float dv0 = dinv[vb], dv1 = dinv[vb + 1], dv2 = dinv[vb + 2], dv3 = dinv[vb + 3];
    float p0 = fmaxf(fmaf(dv0, A0, g0), 0.f) * w0 + fmaxf(fmaf(dv0, A1, g1), 0.f) * w1
             + fmaxf(fmaf(dv0, A2, g2), 0.f) * w2 + fmaxf(fmaf(dv0, A3, g3), 0.f) * w3;
    float p1 = fmaxf(fmaf(dv1, B0, g0), 0.f) * w0 + fmaxf(fmaf(dv1, B1, g1), 0.f) * w1
             + fmaxf(fmaf(dv1, B2, g2), 0.f) * w2 + fmaxf(fmaf(dv1, B3, g3), 0.f) * w3;
    float p2 = fmaxf(fmaf(dv2, C0, g0), 0.f) * w0 + fmaxf(fmaf(dv2, C1, g1), 0.f) * w1
             + fmaxf(fmaf(dv2, C2, g2), 0.f) * w2 + fmaxf(fmaf(dv2, C3, g3), 0.f) * w3;
    float p3 = fmaxf(fmaf(dv3, D0, g0), 0.f) * w0 + fmaxf(fmaf(dv3, D1, g1), 0.f) * w1
             + fmaxf(fmaf(dv3, D2, g2), 0.f) * w2 + fmaxf(fmaf(dv3, D3, g3), 0.f) * w3;
#define REDP(X) X += __shfl_xor(X, 1, 64); X += __shfl_xor(X, 2, 64); X += __shfl_xor(X, 4, 64)
    REDP(p0); REDP(p1); REDP(p2); REDP(p3);
    if (lane == 0) {
        float bb = bfc[0];
        out[vb + 0] = p0 + bb;
        out[vb + 1] = p1 + bb;
        out[vb + 2] = p2 + bb;
        out[vb + 3] = p3 + bb;
    }
}

// ============ launch ============

extern "C" void kernel_launch(void* const* d_in, const int* in_sizes, int n_in,
                              void* d_out, int out_size, void* d_ws, size_t ws_size,
                              hipStream_t stream) {
    const float* x   = (const float*)d_in[0];
    const int*   ei  = (const int*)d_in[1];
    const float* W1  = (const float*)d_in[2];
    const float* b1  = (const float*)d_in[3];
    const float* W2  = (const float*)d_in[4];
    const float* b2  = (const float*)d_in[5];
    const float* Wfc = (const float*)d_in[6];
    const float* bfc = (const float*)d_in[7];
    float* out = (float*)d_out;

    const int E = in_sizes[1] / 2;
    const int TOT = E + N_NODES;
    const int* src = ei;
    const int* dst = ei + E;

    // workspace layout (ints)
    int*   ccount  = (int*)d_ws;                   // 256
    int*   cbase   = ccount + 256;                 // 256 (NBKT+1 used)
    int*   bcur    = cbase + 256;                  // 256
    int*   offsets = bcur + 256;                   // N+1
    int*   srt_src = offsets + N_NODES + 1;        // TOT
    size_t bb_off  = (size_t)(srt_src - (int*)d_ws) + TOT;
    bb_off = (bb_off + 1) & ~(size_t)1;            // 8B-align for uint2
    uint2* bktBuf  = (uint2*)((int*)d_ws + bb_off);        // TOT uint2
    float* dinv    = (float*)((int*)d_ws + bb_off + 2 * (size_t)TOT);  // N
    u16*   h1b     = (u16*)(dinv + N_NODES);       // N*64 bf16
    u16*   h2b     = h1b + (size_t)N_NODES * 64;   // N*32 bf16

    const int NCH = (TOT + CH - 1) / CH;

    hipMemsetAsync(ccount, 0, 256 * sizeof(int), stream);
    coarsehist_k<<<NCH, 256, 0, stream>>>(dst, ccount, E, TOT);
    coarsescan_k<<<1, 256, 0, stream>>>(ccount, cbase, bcur, offsets);
    partition_k<<<NCH, 256, 0, stream>>>(src, dst, bcur, bktBuf, E, TOT);
    buildfill_k<<<NBKT, 256, 0, stream>>>(cbase, bktBuf, offsets, dinv, srt_src);

    gemm1_k<<<N_NODES / 32, 256, 0, stream>>>(x, W1, dinv, h1b);

    layer2_k<<<N_NODES / 8, 256, 0, stream>>>(offsets, srt_src, dinv, h1b, b1, W2, h2b);
    layer3_k<<<N_NODES / 16, 256, 0, stream>>>(offsets, srt_src, dinv, h2b, b2, Wfc,
                                               bfc, out);
}

// Round 7
// 251.933 us; speedup vs baseline: 2.8866x; 1.0310x over previous
//
#include <hip/hip_runtime.h>

#define N_NODES 100000
#define BSH 9                      // 512 nodes per bucket
#define NBKT ((N_NODES + 511) >> BSH)   // 196
#define CH 7168                    // items per partition chunk (56KB LDS stage)

typedef unsigned int u32;
typedef unsigned short u16;

static __device__ __forceinline__ u16 f2bf(float f) {  // round-nearest-even
    union { float f; u32 u; } c; c.f = f;
    u32 r = (c.u + 0x7fffu + ((c.u >> 16) & 1u)) >> 16;
    return (u16)r;
}
static __device__ __forceinline__ void acc2(u32 p, float& a, float& b) {
    union { u32 u; float f; } lo, hi;
    lo.u = p << 16;
    hi.u = p & 0xffff0000u;
    a += lo.f;
    b += hi.f;
}

// ============ CSR build, bucketed ============
// item e in [0,E) = edge (src[e],dst[e]); e in [E,E+N) = self-loop (v,v).

__global__ __launch_bounds__(256) void coarsehist_k(const int* __restrict__ dst,
        int* __restrict__ ccount, int E, int TOT) {
    __shared__ int hist[256];
    hist[threadIdx.x] = 0;
    __syncthreads();
    int base = blockIdx.x * CH;
    int cnt = min(CH, TOT - base);
    for (int i = threadIdx.x; i < cnt; i += 256) {
        int e = base + i;
        int d = (e < E) ? dst[e] : e - E;
        atomicAdd(&hist[d >> BSH], 1);
    }
    __syncthreads();
    if (hist[threadIdx.x]) atomicAdd(&ccount[threadIdx.x], hist[threadIdx.x]);
}

// single block: scan 196 coarse counts -> cbase[0..NBKT], bcur, offsets[N]
__global__ __launch_bounds__(256) void coarsescan_k(const int* __restrict__ ccount,
        int* __restrict__ cbase, int* __restrict__ bcur, int* __restrict__ offsets) {
    __shared__ int ps[256];
    int t = threadIdx.x;
    int c = (t < NBKT) ? ccount[t] : 0;
    ps[t] = c;
    __syncthreads();
    for (int off = 1; off < 256; off <<= 1) {
        int val = ps[t];
        int add = (t >= off) ? ps[t - off] : 0;
        __syncthreads();
        ps[t] = val + add;
        __syncthreads();
    }
    int incl = ps[t], excl = incl - c;
    if (t < NBKT) cbase[t] = excl;
    bcur[t] = (t < NBKT) ? excl : incl;   // t>=NBKT: total (unused)
    if (t == NBKT - 1) cbase[NBKT] = incl;
    if (t == 255) offsets[N_NODES] = ps[255];
}

// chunked LDS counting-sort partition: items -> bktBuf grouped by bucket,
// each (block,bucket) run written contiguously (line-efficient, single-XCD).
__global__ __launch_bounds__(256) void partition_k(const int* __restrict__ src,
        const int* __restrict__ dst, int* __restrict__ bcur,
        uint2* __restrict__ bktBuf, int E, int TOT) {
    __shared__ int hist[256];
    __shared__ int lbase[256];
    __shared__ int gbase[256];
    __shared__ int ps[256];
    __shared__ uint2 stage[CH];
    int t = threadIdx.x;
    int base = blockIdx.x * CH;
    int cnt = min(CH, TOT - base);
    hist[t] = 0;
    __syncthreads();
    // pass A: bucket counts
    for (int i = t; i < cnt; i += 256) {
        int e = base + i;
        int d = (e < E) ? dst[e] : e - E;
        atomicAdd(&hist[d >> BSH], 1);
    }
    __syncthreads();
    // scan -> local bases; reserve global runs
    ps[t] = hist[t];
    __syncthreads();
    for (int off = 1; off < 256; off <<= 1) {
        int val = ps[t];
        int add = (t >= off) ? ps[t - off] : 0;
        __syncthreads();
        ps[t] = val + add;
        __syncthreads();
    }
    lbase[t] = ps[t] - hist[t];
    gbase[t] = atomicAdd(&bcur[t], hist[t]);
    hist[t] = 0;                 // reuse as local cursor
    __syncthreads();
    // pass B: stage bucket-sorted in LDS
    for (int i = t; i < cnt; i += 256) {
        int e = base + i;
        int s, d;
        if (e < E) { s = src[e]; d = dst[e]; }
        else       { s = d = e - E; }
        int b = d >> BSH;
        int lpos = lbase[b] + atomicAdd(&hist[b], 1);
        stage[lpos] = make_uint2((u32)s, (u32)d);
    }
    __syncthreads();
    // pass C: contiguous run writes
    for (int i = t; i < cnt; i += 256) {
        uint2 p = stage[i];
        int b = (int)p.y >> BSH;
        bktBuf[gbase[b] + (i - lbase[b])] = p;
    }
}

// one block per bucket: local deg histogram+scan -> offsets, dinv; then
// scatter srt_src inside the block-exclusive window.
__global__ __launch_bounds__(256) void buildfill_k(const int* __restrict__ cbase,
        const uint2* __restrict__ bktBuf, int* __restrict__ offsets,
        float* __restrict__ dinv, int* __restrict__ srt_src) {
    __shared__ int hist[512];
    __shared__ int hscan[512];
    __shared__ int cur[512];
    __shared__ int ps[256];
    int t = threadIdx.x;
    int b = blockIdx.x;
    int v0 = b << BSH;
    int nv = min(512, N_NODES - v0);
    hist[t] = 0; hist[t + 256] = 0;
    cur[t] = 0;  cur[t + 256] = 0;
    __syncthreads();
    int beg = cbase[b], endi = cbase[b + 1];
    for (int i = beg + t; i < endi; i += 256)
        atomicAdd(&hist[(int)bktBuf[i].y - v0], 1);
    __syncthreads();
    // exclusive scan of hist[0..511] (pairs + Hillis-Steele over 256)
    int a = hist[2 * t], bb = hist[2 * t + 1];
    int own = a + bb;
    ps[t] = own;
    __syncthreads();
    for (int off = 1; off < 256; off <<= 1) {
        int val = ps[t];
        int add = (t >= off) ? ps[t - off] : 0;
        __syncthreads();
        ps[t] = val + add;
        __syncthreads();
    }
    int excl2 = ps[t] - own;
    hscan[2 * t] = excl2;
    hscan[2 * t + 1] = excl2 + a;
    __syncthreads();
    // offsets + dinv (hist includes the self-loop -> deg+1)
    for (int j = t; j < nv; j += 256) {
        offsets[v0 + j] = beg + hscan[j];
        dinv[v0 + j] = rsqrtf((float)hist[j]);
    }
    // scatter within [beg, endi) — block-exclusive window
    for (int i = beg + t; i < endi; i += 256) {
        uint2 p = bktBuf[i];
        int j = (int)p.y - v0;
        int pos = atomicAdd(&cur[j], 1);
        srt_src[beg + hscan[j] + pos] = (int)p.x;
    }
}

// ============ GEMM1: h1b[N,64](bf16) = dinv[row] * (x[N,128] @ W1) ============
// 8 rows accumulated concurrently per wave: each LDS read of W feeds 8 FMAs
// (8x less LDS traffic than row-sequential); x operands are wave-uniform
// scalar loads (SGPR broadcast into v_fmac).

__global__ __launch_bounds__(256) void gemm1_k(const float* __restrict__ x,
                                               const float* __restrict__ W1,
                                               const float* __restrict__ dinv,
                                               u16* __restrict__ h1b) {
    __shared__ float Ws[128 * 64];
    for (int i = threadIdx.x; i < 128 * 64; i += 256) Ws[i] = W1[i];
    __syncthreads();
    int lane = threadIdx.x & 63;
    int base = __builtin_amdgcn_readfirstlane(
        (blockIdx.x * 4 + (threadIdx.x >> 6)) * 8);   // grid = N/32 exactly
    const float* xr = x + (size_t)base * 128;
    float acc[8] = {0.f, 0.f, 0.f, 0.f, 0.f, 0.f, 0.f, 0.f};
#pragma unroll 4
    for (int k = 0; k < 128; ++k) {
        float w = Ws[k * 64 + lane];
#pragma unroll
        for (int r = 0; r < 8; ++r)
            acc[r] = fmaf(xr[r * 128 + k], w, acc[r]);
    }
#pragma unroll
    for (int r = 0; r < 8; ++r)
        h1b[(size_t)(base + r) * 64 + lane] = f2bf(dinv[base + r] * acc[r]);
}

// ============ layer2: h2b = dinv * (relu(dinv*agg + b1) @ W2) ============

__global__ __launch_bounds__(256) void layer2_k(const int* __restrict__ offsets,
        const int* __restrict__ srt_src, const float* __restrict__ dinv,
        const u16* __restrict__ h1b, const float* __restrict__ b1,
        const float* __restrict__ W2, u16* __restrict__ h2b) {
    __shared__ float W2s[64 * 32];
    __shared__ float b1s[64];
    for (int i = threadIdx.x; i < 64 * 32; i += 256) W2s[i] = W2[i];
    if (threadIdx.x < 64) b1s[threadIdx.x] = b1[threadIdx.x];
    __syncthreads();
    int lane = threadIdx.x & 63;
    int f = lane & 15, q = lane >> 4;
    int v0 = blockIdx.x * 8 + (threadIdx.x >> 6) * 2;   // grid = N/8
    int v1 = v0 + 1;
    int i0 = offsets[v0], e0 = offsets[v1], e1 = offsets[v1 + 1];
    int i1 = e0;
    const uint2* rows = (const uint2*)h1b;              // row s = rows + s*16
    float a0 = 0.f, a1 = 0.f, a2 = 0.f, a3 = 0.f;       // node0
    float c0 = 0.f, c1 = 0.f, c2 = 0.f, c3 = 0.f;       // node1
    while (i0 + 8 <= e0 && i1 + 8 <= e1) {
        int sA = srt_src[i0 + q];
        int sB = srt_src[i0 + 4 + q];
        int sC = srt_src[i1 + q];
        int sD = srt_src[i1 + 4 + q];
        uint2 pA = rows[sA * 16 + f];
        uint2 pB = rows[sB * 16 + f];
        uint2 pC = rows[sC * 16 + f];
        uint2 pD = rows[sD * 16 + f];
        acc2(pA.x, a0, a1); acc2(pA.y, a2, a3);
        acc2(pB.x, a0, a1); acc2(pB.y, a2, a3);
        acc2(pC.x, c0, c1); acc2(pC.y, c2, c3);
        acc2(pD.x, c0, c1); acc2(pD.y, c2, c3);
        i0 += 8; i1 += 8;
    }
    for (; i0 + 8 <= e0; i0 += 8) {
        int sA = srt_src[i0 + q], sB = srt_src[i0 + 4 + q];
        uint2 pA = rows[sA * 16 + f], pB = rows[sB * 16 + f];
        acc2(pA.x, a0, a1); acc2(pA.y, a2, a3);
        acc2(pB.x, a0, a1); acc2(pB.y, a2, a3);
    }
    for (; i0 < e0; i0 += 4) {
        int j = i0 + q;
        if (j < e0) {
            int s = srt_src[j];
            uint2 p = rows[s * 16 + f];
            acc2(p.x, a0, a1); acc2(p.y, a2, a3);
        }
    }
    for (; i1 + 8 <= e1; i1 += 8) {
        int sA = srt_src[i1 + q], sB = srt_src[i1 + 4 + q];
        uint2 pA = rows[sA * 16 + f], pB = rows[sB * 16 + f];
        acc2(pA.x, c0, c1); acc2(pA.y, c2, c3);
        acc2(pB.x, c0, c1); acc2(pB.y, c2, c3);
    }
    for (; i1 < e1; i1 += 4) {
        int j = i1 + q;
        if (j < e1) {
            int s = srt_src[j];
            uint2 p = rows[s * 16 + f];
            acc2(p.x, c0, c1); acc2(p.y, c2, c3);
        }
    }
    a0 += __shfl_xor(a0, 16, 64); a0 += __shfl_xor(a0, 32, 64);
    a1 += __shfl_xor(a1, 16, 64); a1 += __shfl_xor(a1, 32, 64);
    a2 += __shfl_xor(a2, 16, 64); a2 += __shfl_xor(a2, 32, 64);
    a3 += __shfl_xor(a3, 16, 64); a3 += __shfl_xor(a3, 32, 64);
    c0 += __shfl_xor(c0, 16, 64); c0 += __shfl_xor(c0, 32, 64);
    c1 += __shfl_xor(c1, 16, 64); c1 += __shfl_xor(c1, 32, 64);
    c2 += __shfl_xor(c2, 16, 64); c2 += __shfl_xor(c2, 32, 64);
    c3 += __shfl_xor(c3, 16, 64); c3 += __shfl_xor(c3, 32, 64);
    bool lo = (lane < 32);
    float dv = lo ? dinv[v0] : dinv[v1];
    float t0 = lo ? a0 : c0;
    float t1 = lo ? a1 : c1;
    float t2 = lo ? a2 : c2;
    float t3 = lo ? a3 : c3;
    float r0 = fmaxf(fmaf(dv, t0, b1s[4 * f + 0]), 0.f);
    float r1 = fmaxf(fmaf(dv, t1, b1s[4 * f + 1]), 0.f);
    float r2 = fmaxf(fmaf(dv, t2, b1s[4 * f + 2]), 0.f);
    float r3 = fmaxf(fmaf(dv, t3, b1s[4 * f + 3]), 0.f);
    int c = lane & 31;
    float o = 0.f;
#pragma unroll
    for (int j2 = 0; j2 < 16; ++j2) {
        float R0 = __shfl(r0, j2, 16);
        float R1 = __shfl(r1, j2, 16);
        float R2 = __shfl(r2, j2, 16);
        float R3 = __shfl(r3, j2, 16);
        o = fmaf(R0, W2s[(4 * j2 + 0) * 32 + c], o);
        o = fmaf(R1, W2s[(4 * j2 + 1) * 32 + c], o);
        o = fmaf(R2, W2s[(4 * j2 + 2) * 32 + c], o);
        o = fmaf(R3, W2s[(4 * j2 + 3) * 32 + c], o);
    }
    int vst = lo ? v0 : v1;
    h2b[vst * 32 + c] = f2bf(dv * o);
}

// ============ layer3: out = relu(dinv*agg(h2b) + b2) @ Wfc + bfc ============

#define GATH3(ii, A, B, C, D) { \
    int s_ = srt_src[(ii) + oc]; \
    uint2 p_ = rows[s_ * 8 + f]; \
    acc2(p_.x, A, B); acc2(p_.y, C, D); }

__global__ __launch_bounds__(256) void layer3_k(const int* __restrict__ offsets,
        const int* __restrict__ srt_src, const float* __restrict__ dinv,
        const u16* __restrict__ h2b, const float* __restrict__ b2,
        const float* __restrict__ Wfc, const float* __restrict__ bfc,
        float* __restrict__ out) {
    int lane = threadIdx.x & 63;
    int f = lane & 7, oc = lane >> 3;
    int vb = blockIdx.x * 16 + (threadIdx.x >> 6) * 4;   // grid = N/16
    int o0 = offsets[vb], o1 = offsets[vb + 1], o2 = offsets[vb + 2];
    int o3 = offsets[vb + 3], o4 = offsets[vb + 4];
    int i0 = o0, e0 = o1, i1 = o1, e1 = o2, i2 = o2, e2 = o3, i3 = o3, e3 = o4;
    const uint2* rows = (const uint2*)h2b;               // row s = rows + s*8
    float A0=0.f,A1=0.f,A2=0.f,A3=0.f, B0=0.f,B1=0.f,B2=0.f,B3=0.f;
    float C0=0.f,C1=0.f,C2=0.f,C3=0.f, D0=0.f,D1=0.f,D2=0.f,D3=0.f;
    while (i0 + 8 <= e0 && i1 + 8 <= e1 && i2 + 8 <= e2 && i3 + 8 <= e3) {
        GATH3(i0, A0, A1, A2, A3);
        GATH3(i1, B0, B1, B2, B3);
        GATH3(i2, C0, C1, C2, C3);
        GATH3(i3, D0, D1, D2, D3);
        i0 += 8; i1 += 8; i2 += 8; i3 += 8;
    }
    while (i0 + 8 <= e0) { GATH3(i0, A0, A1, A2, A3); i0 += 8; }
    if (i0 + oc < e0)    { GATH3(i0, A0, A1, A2, A3); }
    while (i1 + 8 <= e1) { GATH3(i1, B0, B1, B2, B3); i1 += 8; }
    if (i1 + oc < e1)    { GATH3(i1, B0, B1, B2, B3); }
    while (i2 + 8 <= e2) { GATH3(i2, C0, C1, C2, C3); i2 += 8; }
    if (i2 + oc < e2)    { GATH3(i2, C0, C1, C2, C3); }
    while (i3 + 8 <= e3) { GATH3(i3, D0, D1, D2, D3); i3 += 8; }
    if (i3 + oc < e3)    { GATH3(i3, D0, D1, D2, D3); }
#define RED3(X) X += __shfl_xor(X, 8, 64); X += __shfl_xor(X, 16, 64); X += __shfl_xor(X, 32, 64)
    RED3(A0); RED3(A1); RED3(A2); RED3(A3);
    RED3(B0); RED3(B1); RED3(B2); RED3(B3);
    RED3(C0); RED3(C1); RED3(C2); RED3(C3);
    RED3(D0); RED3(D1); RED3(D2); RED3(D3);
    float w0 = Wfc[4 * f + 0], w1 = Wfc[4 * f + 1];
    float w2 = Wfc[4 * f + 2], w3 = Wfc[4 * f + 3];
    float g0 = b2[4 * f + 0], g1 = b2[4 * f + 1];
    float g2 = b2[4 * f + 2], g3 = b2[4 * f + 3];
    float dv0 = dinv[vb], dv1 = dinv[vb + 1], dv2 = dinv[vb + 2], dv3 = dinv[vb + 3];
    float p0 = fmaxf(fmaf(dv0, A0, g0), 0.f) * w0 + fmaxf(fmaf(dv0, A1, g1), 0.f) * w1
             + fmaxf(fmaf(dv0, A2, g2), 0.f) * w2 + fmaxf(fmaf(dv0, A3, g3), 0.f) * w3;
    float p1 = fmaxf(fmaf(dv1, B0, g0), 0.f) * w0 + fmaxf(fmaf(dv1, B1, g1), 0.f) * w1
             + fmaxf(fmaf(dv1, B2, g2), 0.f) * w2 + fmaxf(fmaf(dv1, B3, g3), 0.f) * w3;
    float p2 = fmaxf(fmaf(dv2, C0, g0), 0.f) * w0 + fmaxf(fmaf(dv2, C1, g1), 0.f) * w1
             + fmaxf(fmaf(dv2, C2, g2), 0.f) * w2 + fmaxf(fmaf(dv2, C3, g3), 0.f) * w3;
    float p3 = fmaxf(fmaf(dv3, D0, g0), 0.f) * w0 + fmaxf(fmaf(dv3, D1, g1), 0.f) * w1
             + fmaxf(fmaf(dv3, D2, g2), 0.f) * w2 + fmaxf(fmaf(dv3, D3, g3), 0.f) * w3;
#define REDP(X) X += __shfl_xor(X, 1, 64); X += __shfl_xor(X, 2, 64); X += __shfl_xor(X, 4, 64)
    REDP(p0); REDP(p1); REDP(p2); REDP(p3);
    if (lane == 0) {
        float bb = bfc[0];
        out[vb + 0] = p0 + bb;
        out[vb + 1] = p1 + bb;
        out[vb + 2] = p2 + bb;
        out[vb + 3] = p3 + bb;
    }
}

// ============ launch ============

extern "C" void kernel_launch(void* const* d_in, const int* in_sizes, int n_in,
                              void* d_out, int out_size, void* d_ws, size_t ws_size,
                              hipStream_t stream) {
    const float* x   = (const float*)d_in[0];
    const int*   ei  = (const int*)d_in[1];
    const float* W1  = (const float*)d_in[2];
    const float* b1  = (const float*)d_in[3];
    const float* W2  = (const float*)d_in[4];
    const float* b2  = (const float*)d_in[5];
    const float* Wfc = (const float*)d_in[6];
    const float* bfc = (const float*)d_in[7];
    float* out = (float*)d_out;

    const int E = in_sizes[1] / 2;
    const int TOT = E + N_NODES;
    const int* src = ei;
    const int* dst = ei + E;

    // workspace layout (ints)
    int*   ccount  = (int*)d_ws;                   // 256
    int*   cbase   = ccount + 256;                 // 256 (NBKT+1 used)
    int*   bcur    = cbase + 256;                  // 256
    int*   offsets = bcur + 256;                   // N+1
    int*   srt_src = offsets + N_NODES + 1;        // TOT
    size_t bb_off  = (size_t)(srt_src - (int*)d_ws) + TOT;
    bb_off = (bb_off + 1) & ~(size_t)1;            // 8B-align for uint2
    uint2* bktBuf  = (uint2*)((int*)d_ws + bb_off);        // TOT uint2
    float* dinv    = (float*)((int*)d_ws + bb_off + 2 * (size_t)TOT);  // N
    u16*   h1b     = (u16*)(dinv + N_NODES);       // N*64 bf16
    u16*   h2b     = h1b + (size_t)N_NODES * 64;   // N*32 bf16

    const int NCH = (TOT + CH - 1) / CH;

    hipMemsetAsync(ccount, 0, 256 * sizeof(int), stream);
    coarsehist_k<<<NCH, 256, 0, stream>>>(dst, ccount, E, TOT);
    coarsescan_k<<<1, 256, 0, stream>>>(ccount, cbase, bcur, offsets);
    partition_k<<<NCH, 256, 0, stream>>>(src, dst, bcur, bktBuf, E, TOT);
    buildfill_k<<<NBKT, 256, 0, stream>>>(cbase, bktBuf, offsets, dinv, srt_src);

    gemm1_k<<<N_NODES / 32, 256, 0, stream>>>(x, W1, dinv, h1b);

    layer2_k<<<N_NODES / 8, 256, 0, stream>>>(offsets, srt_src, dinv, h1b, b1, W2, h2b);
    layer3_k<<<N_NODES / 16, 256, 0, stream>>>(offsets, srt_src, dinv, h2b, b2, Wfc,
                                               bfc, out);
}

// Round 8
// 210.176 us; speedup vs baseline: 3.4601x; 1.1987x over previous
//
#include <hip/hip_runtime.h>

#define N_NODES 100000
#define BSH 9                      // 512 nodes per bucket
#define NBKT ((N_NODES + 511) >> BSH)   // 196
#define CH 7168                    // items per partition chunk (56KB LDS stage)

typedef unsigned int u32;
typedef unsigned short u16;
typedef __attribute__((ext_vector_type(8))) short s8v;   // 8 bf16 (4 VGPRs)
typedef __attribute__((ext_vector_type(4))) float f4v;   // 4 f32 acc

static __device__ __forceinline__ u16 f2bf(float f) {  // round-nearest-even
    union { float f; u32 u; } c; c.f = f;
    u32 r = (c.u + 0x7fffu + ((c.u >> 16) & 1u)) >> 16;
    return (u16)r;
}
static __device__ __forceinline__ float bf2f_u(u16 h) {
    union { u32 u; float f; } c; c.u = ((u32)h) << 16;
    return c.f;
}
static __device__ __forceinline__ void acc2(u32 p, float& a, float& b) {
    union { u32 u; float f; } lo, hi;
    lo.u = p << 16;
    hi.u = p & 0xffff0000u;
    a += lo.f;
    b += hi.f;
}

// ============ CSR build, bucketed ============
// item e in [0,E) = edge (src[e],dst[e]); e in [E,E+N) = self-loop (v,v).

__global__ __launch_bounds__(256) void coarsehist_k(const int* __restrict__ dst,
        int* __restrict__ ccount, int E, int TOT) {
    __shared__ int hist[256];
    hist[threadIdx.x] = 0;
    __syncthreads();
    int base = blockIdx.x * CH;
    int cnt = min(CH, TOT - base);
    for (int i = threadIdx.x; i < cnt; i += 256) {
        int e = base + i;
        int d = (e < E) ? dst[e] : e - E;
        atomicAdd(&hist[d >> BSH], 1);
    }
    __syncthreads();
    if (hist[threadIdx.x]) atomicAdd(&ccount[threadIdx.x], hist[threadIdx.x]);
}

// single block: scan 196 coarse counts -> cbase[0..NBKT], bcur, offsets[N]
__global__ __launch_bounds__(256) void coarsescan_k(const int* __restrict__ ccount,
        int* __restrict__ cbase, int* __restrict__ bcur, int* __restrict__ offsets) {
    __shared__ int ps[256];
    int t = threadIdx.x;
    int c = (t < NBKT) ? ccount[t] : 0;
    ps[t] = c;
    __syncthreads();
    for (int off = 1; off < 256; off <<= 1) {
        int val = ps[t];
        int add = (t >= off) ? ps[t - off] : 0;
        __syncthreads();
        ps[t] = val + add;
        __syncthreads();
    }
    int incl = ps[t], excl = incl - c;
    if (t < NBKT) cbase[t] = excl;
    bcur[t] = (t < NBKT) ? excl : incl;   // t>=NBKT: total (unused)
    if (t == NBKT - 1) cbase[NBKT] = incl;
    if (t == 255) offsets[N_NODES] = ps[255];
}

// chunked LDS counting-sort partition: items -> bktBuf grouped by bucket,
// each (block,bucket) run written contiguously (line-efficient, single-XCD).
__global__ __launch_bounds__(256) void partition_k(const int* __restrict__ src,
        const int* __restrict__ dst, int* __restrict__ bcur,
        uint2* __restrict__ bktBuf, int E, int TOT) {
    __shared__ int hist[256];
    __shared__ int lbase[256];
    __shared__ int gbase[256];
    __shared__ int ps[256];
    __shared__ uint2 stage[CH];
    int t = threadIdx.x;
    int base = blockIdx.x * CH;
    int cnt = min(CH, TOT - base);
    hist[t] = 0;
    __syncthreads();
    // pass A: bucket counts
    for (int i = t; i < cnt; i += 256) {
        int e = base + i;
        int d = (e < E) ? dst[e] : e - E;
        atomicAdd(&hist[d >> BSH], 1);
    }
    __syncthreads();
    // scan -> local bases; reserve global runs
    ps[t] = hist[t];
    __syncthreads();
    for (int off = 1; off < 256; off <<= 1) {
        int val = ps[t];
        int add = (t >= off) ? ps[t - off] : 0;
        __syncthreads();
        ps[t] = val + add;
        __syncthreads();
    }
    lbase[t] = ps[t] - hist[t];
    gbase[t] = atomicAdd(&bcur[t], hist[t]);
    hist[t] = 0;                 // reuse as local cursor
    __syncthreads();
    // pass B: stage bucket-sorted in LDS
    for (int i = t; i < cnt; i += 256) {
        int e = base + i;
        int s, d;
        if (e < E) { s = src[e]; d = dst[e]; }
        else       { s = d = e - E; }
        int b = d >> BSH;
        int lpos = lbase[b] + atomicAdd(&hist[b], 1);
        stage[lpos] = make_uint2((u32)s, (u32)d);
    }
    __syncthreads();
    // pass C: contiguous run writes
    for (int i = t; i < cnt; i += 256) {
        uint2 p = stage[i];
        int b = (int)p.y >> BSH;
        bktBuf[gbase[b] + (i - lbase[b])] = p;
    }
}

// one block per bucket: local deg histogram+scan -> offsets, dinv; then
// scatter srt_src inside the block-exclusive window.
__global__ __launch_bounds__(256) void buildfill_k(const int* __restrict__ cbase,
        const uint2* __restrict__ bktBuf, int* __restrict__ offsets,
        float* __restrict__ dinv, int* __restrict__ srt_src) {
    __shared__ int hist[512];
    __shared__ int hscan[512];
    __shared__ int cur[512];
    __shared__ int ps[256];
    int t = threadIdx.x;
    int b = blockIdx.x;
    int v0 = b << BSH;
    int nv = min(512, N_NODES - v0);
    hist[t] = 0; hist[t + 256] = 0;
    cur[t] = 0;  cur[t + 256] = 0;
    __syncthreads();
    int beg = cbase[b], endi = cbase[b + 1];
    for (int i = beg + t; i < endi; i += 256)
        atomicAdd(&hist[(int)bktBuf[i].y - v0], 1);
    __syncthreads();
    // exclusive scan of hist[0..511] (pairs + Hillis-Steele over 256)
    int a = hist[2 * t], bb = hist[2 * t + 1];
    int own = a + bb;
    ps[t] = own;
    __syncthreads();
    for (int off = 1; off < 256; off <<= 1) {
        int val = ps[t];
        int add = (t >= off) ? ps[t - off] : 0;
        __syncthreads();
        ps[t] = val + add;
        __syncthreads();
    }
    int excl2 = ps[t] - own;
    hscan[2 * t] = excl2;
    hscan[2 * t + 1] = excl2 + a;
    __syncthreads();
    // offsets + dinv (hist includes the self-loop -> deg+1)
    for (int j = t; j < nv; j += 256) {
        offsets[v0 + j] = beg + hscan[j];
        dinv[v0 + j] = rsqrtf((float)hist[j]);
    }
    // scatter within [beg, endi) — block-exclusive window
    for (int i = beg + t; i < endi; i += 256) {
        uint2 p = bktBuf[i];
        int j = (int)p.y - v0;
        int pos = atomicAdd(&cur[j], 1);
        srt_src[beg + hscan[j] + pos] = (int)p.x;
    }
}

// ============ GEMM1 (MFMA): h1b[N,64](bf16) = dinv[row] * (x[N,128] @ W1) ====
// Split-bf16 (hi+lo) for both operands -> ~f32 precision via 3 MFMAs/tile.
// Per wave: 32 rows x 64 cols. A-frags from coalesced float4 global loads
// (one 128B line per (row,kstep)); B staged pre-swizzled in LDS (32KB).
// Layouts (16x16x32): A row=lane&15, k=(lane>>4)*8+j; B col=lane&15,
// k=(lane>>4)*8+j; D col=lane&15, row=(lane>>4)*4+reg  [m89-verified].

static __device__ __forceinline__ void split8(const float* __restrict__ xp,
                                              s8v& hi, s8v& lo) {
    float4 v0 = *(const float4*)xp;
    float4 v1 = *(const float4*)(xp + 4);
    float xv[8] = {v0.x, v0.y, v0.z, v0.w, v1.x, v1.y, v1.z, v1.w};
#pragma unroll
    for (int j = 0; j < 8; ++j) {
        u16 h = f2bf(xv[j]);
        hi[j] = (short)h;
        lo[j] = (short)f2bf(xv[j] - bf2f_u(h));
    }
}

__global__ __launch_bounds__(256) void gemm1_k(const float* __restrict__ x,
                                               const float* __restrict__ W1,
                                               const float* __restrict__ dinv,
                                               u16* __restrict__ h1b) {
    // Bs[h][kstep][ct][(kgroup*16+col)*8+kk]
    __shared__ __attribute__((aligned(16))) short Bs[2][4][4][512];
    int t = threadIdx.x;
    for (int i = t; i < 128 * 64; i += 256) {
        int k = i >> 6, c = i & 63;
        float w = W1[i];
        u16 h = f2bf(w);
        u16 l = f2bf(w - bf2f_u(h));
        int ks = k >> 5, kg = (k >> 3) & 3, kk = k & 7;
        int ct = c >> 4, col = c & 15;
        int idx = (kg * 16 + col) * 8 + kk;
        Bs[0][ks][ct][idx] = (short)h;
        Bs[1][ks][ct][idx] = (short)l;
    }
    __syncthreads();

    int lane = t & 63;
    int rows0 = (blockIdx.x * 4 + (t >> 6)) * 32;
    if (rows0 >= N_NODES) return;

    f4v acc[2][4];
#pragma unroll
    for (int rt = 0; rt < 2; ++rt)
#pragma unroll
        for (int ct = 0; ct < 4; ++ct)
            acc[rt][ct] = (f4v){0.f, 0.f, 0.f, 0.f};

    int arow = lane & 15;
    int kgl = lane >> 4;
#pragma unroll
    for (int ks = 0; ks < 4; ++ks) {
        s8v bh[4], bl[4];
#pragma unroll
        for (int ct = 0; ct < 4; ++ct) {
            bh[ct] = *(const s8v*)&Bs[0][ks][ct][lane * 8];
            bl[ct] = *(const s8v*)&Bs[1][ks][ct][lane * 8];
        }
#pragma unroll
        for (int rt = 0; rt < 2; ++rt) {
            s8v ah, al;
            const float* xp = x + (size_t)(rows0 + rt * 16 + arow) * 128
                                + ks * 32 + kgl * 8;
            split8(xp, ah, al);
#pragma unroll
            for (int ct = 0; ct < 4; ++ct) {
                acc[rt][ct] = __builtin_amdgcn_mfma_f32_16x16x32_bf16(
                    ah, bh[ct], acc[rt][ct], 0, 0, 0);
                acc[rt][ct] = __builtin_amdgcn_mfma_f32_16x16x32_bf16(
                    ah, bl[ct], acc[rt][ct], 0, 0, 0);
                acc[rt][ct] = __builtin_amdgcn_mfma_f32_16x16x32_bf16(
                    al, bh[ct], acc[rt][ct], 0, 0, 0);
            }
        }
    }

#pragma unroll
    for (int rt = 0; rt < 2; ++rt) {
        int rbase = rows0 + rt * 16 + ((lane >> 4) << 2);
        float dv[4];
#pragma unroll
        for (int r = 0; r < 4; ++r) dv[r] = dinv[rbase + r];
#pragma unroll
        for (int ct = 0; ct < 4; ++ct) {
            int col = ct * 16 + (lane & 15);
#pragma unroll
            for (int r = 0; r < 4; ++r)
                h1b[(size_t)(rbase + r) * 64 + col] = f2bf(acc[rt][ct][r] * dv[r]);
        }
    }
}

// ============ layer2: h2b = dinv * (relu(dinv*agg + b1) @ W2) ============

__global__ __launch_bounds__(256) void layer2_k(const int* __restrict__ offsets,
        const int* __restrict__ srt_src, const float* __restrict__ dinv,
        const u16* __restrict__ h1b, const float* __restrict__ b1,
        const float* __restrict__ W2, u16* __restrict__ h2b) {
    __shared__ float W2s[64 * 32];
    __shared__ float b1s[64];
    for (int i = threadIdx.x; i < 64 * 32; i += 256) W2s[i] = W2[i];
    if (threadIdx.x < 64) b1s[threadIdx.x] = b1[threadIdx.x];
    __syncthreads();
    int lane = threadIdx.x & 63;
    int f = lane & 15, q = lane >> 4;
    int v0 = blockIdx.x * 8 + (threadIdx.x >> 6) * 2;   // grid = N/8
    int v1 = v0 + 1;
    int i0 = offsets[v0], e0 = offsets[v1], e1 = offsets[v1 + 1];
    int i1 = e0;
    const uint2* rows = (const uint2*)h1b;              // row s = rows + s*16
    float a0 = 0.f, a1 = 0.f, a2 = 0.f, a3 = 0.f;       // node0
    float c0 = 0.f, c1 = 0.f, c2 = 0.f, c3 = 0.f;       // node1
    while (i0 + 8 <= e0 && i1 + 8 <= e1) {
        int sA = srt_src[i0 + q];
        int sB = srt_src[i0 + 4 + q];
        int sC = srt_src[i1 + q];
        int sD = srt_src[i1 + 4 + q];
        uint2 pA = rows[sA * 16 + f];
        uint2 pB = rows[sB * 16 + f];
        uint2 pC = rows[sC * 16 + f];
        uint2 pD = rows[sD * 16 + f];
        acc2(pA.x, a0, a1); acc2(pA.y, a2, a3);
        acc2(pB.x, a0, a1); acc2(pB.y, a2, a3);
        acc2(pC.x, c0, c1); acc2(pC.y, c2, c3);
        acc2(pD.x, c0, c1); acc2(pD.y, c2, c3);
        i0 += 8; i1 += 8;
    }
    for (; i0 + 8 <= e0; i0 += 8) {
        int sA = srt_src[i0 + q], sB = srt_src[i0 + 4 + q];
        uint2 pA = rows[sA * 16 + f], pB = rows[sB * 16 + f];
        acc2(pA.x, a0, a1); acc2(pA.y, a2, a3);
        acc2(pB.x, a0, a1); acc2(pB.y, a2, a3);
    }
    for (; i0 < e0; i0 += 4) {
        int j = i0 + q;
        if (j < e0) {
            int s = srt_src[j];
            uint2 p = rows[s * 16 + f];
            acc2(p.x, a0, a1); acc2(p.y, a2, a3);
        }
    }
    for (; i1 + 8 <= e1; i1 += 8) {
        int sA = srt_src[i1 + q], sB = srt_src[i1 + 4 + q];
        uint2 pA = rows[sA * 16 + f], pB = rows[sB * 16 + f];
        acc2(pA.x, c0, c1); acc2(pA.y, c2, c3);
        acc2(pB.x, c0, c1); acc2(pB.y, c2, c3);
    }
    for (; i1 < e1; i1 += 4) {
        int j = i1 + q;
        if (j < e1) {
            int s = srt_src[j];
            uint2 p = rows[s * 16 + f];
            acc2(p.x, c0, c1); acc2(p.y, c2, c3);
        }
    }
    a0 += __shfl_xor(a0, 16, 64); a0 += __shfl_xor(a0, 32, 64);
    a1 += __shfl_xor(a1, 16, 64); a1 += __shfl_xor(a1, 32, 64);
    a2 += __shfl_xor(a2, 16, 64); a2 += __shfl_xor(a2, 32, 64);
    a3 += __shfl_xor(a3, 16, 64); a3 += __shfl_xor(a3, 32, 64);
    c0 += __shfl_xor(c0, 16, 64); c0 += __shfl_xor(c0, 32, 64);
    c1 += __shfl_xor(c1, 16, 64); c1 += __shfl_xor(c1, 32, 64);
    c2 += __shfl_xor(c2, 16, 64); c2 += __shfl_xor(c2, 32, 64);
    c3 += __shfl_xor(c3, 16, 64); c3 += __shfl_xor(c3, 32, 64);
    bool lo = (lane < 32);
    float dv = lo ? dinv[v0] : dinv[v1];
    float t0 = lo ? a0 : c0;
    float t1 = lo ? a1 : c1;
    float t2 = lo ? a2 : c2;
    float t3 = lo ? a3 : c3;
    float r0 = fmaxf(fmaf(dv, t0, b1s[4 * f + 0]), 0.f);
    float r1 = fmaxf(fmaf(dv, t1, b1s[4 * f + 1]), 0.f);
    float r2 = fmaxf(fmaf(dv, t2, b1s[4 * f + 2]), 0.f);
    float r3 = fmaxf(fmaf(dv, t3, b1s[4 * f + 3]), 0.f);
    int c = lane & 31;
    float o = 0.f;
#pragma unroll
    for (int j2 = 0; j2 < 16; ++j2) {
        float R0 = __shfl(r0, j2, 16);
        float R1 = __shfl(r1, j2, 16);
        float R2 = __shfl(r2, j2, 16);
        float R3 = __shfl(r3, j2, 16);
        o = fmaf(R0, W2s[(4 * j2 + 0) * 32 + c], o);
        o = fmaf(R1, W2s[(4 * j2 + 1) * 32 + c], o);
        o = fmaf(R2, W2s[(4 * j2 + 2) * 32 + c], o);
        o = fmaf(R3, W2s[(4 * j2 + 3) * 32 + c], o);
    }
    int vst = lo ? v0 : v1;
    h2b[vst * 32 + c] = f2bf(dv * o);
}

// ============ layer3: out = relu(dinv*agg(h2b) + b2) @ Wfc + bfc ============

#define GATH3(ii, A, B, C, D) { \
    int s_ = srt_src[(ii) + oc]; \
    uint2 p_ = rows[s_ * 8 + f]; \
    acc2(p_.x, A, B); acc2(p_.y, C, D); }

__global__ __launch_bounds__(256) void layer3_k(const int* __restrict__ offsets,
        const int* __restrict__ srt_src, const float* __restrict__ dinv,
        const u16* __restrict__ h2b, const float* __restrict__ b2,
        const float* __restrict__ Wfc, const float* __restrict__ bfc,
        float* __restrict__ out) {
    int lane = threadIdx.x & 63;
    int f = lane & 7, oc = lane >> 3;
    int vb = blockIdx.x * 16 + (threadIdx.x >> 6) * 4;   // grid = N/16
    int o0 = offsets[vb], o1 = offsets[vb + 1], o2 = offsets[vb + 2];
    int o3 = offsets[vb + 3], o4 = offsets[vb + 4];
    int i0 = o0, e0 = o1, i1 = o1, e1 = o2, i2 = o2, e2 = o3, i3 = o3, e3 = o4;
    const uint2* rows = (const uint2*)h2b;               // row s = rows + s*8
    float A0=0.f,A1=0.f,A2=0.f,A3=0.f, B0=0.f,B1=0.f,B2=0.f,B3=0.f;
    float C0=0.f,C1=0.f,C2=0.f,C3=0.f, D0=0.f,D1=0.f,D2=0.f,D3=0.f;
    while (i0 + 8 <= e0 && i1 + 8 <= e1 && i2 + 8 <= e2 && i3 + 8 <= e3) {
        GATH3(i0, A0, A1, A2, A3);
        GATH3(i1, B0, B1, B2, B3);
        GATH3(i2, C0, C1, C2, C3);
        GATH3(i3, D0, D1, D2, D3);
        i0 += 8; i1 += 8; i2 += 8; i3 += 8;
    }
    while (i0 + 8 <= e0) { GATH3(i0, A0, A1, A2, A3); i0 += 8; }
    if (i0 + oc < e0)    { GATH3(i0, A0, A1, A2, A3); }
    while (i1 + 8 <= e1) { GATH3(i1, B0, B1, B2, B3); i1 += 8; }
    if (i1 + oc < e1)    { GATH3(i1, B0, B1, B2, B3); }
    while (i2 + 8 <= e2) { GATH3(i2, C0, C1, C2, C3); i2 += 8; }
    if (i2 + oc < e2)    { GATH3(i2, C0, C1, C2, C3); }
    while (i3 + 8 <= e3) { GATH3(i3, D0, D1, D2, D3); i3 += 8; }
    if (i3 + oc < e3)    { GATH3(i3, D0, D1, D2, D3); }
#define RED3(X) X += __shfl_xor(X, 8, 64); X += __shfl_xor(X, 16, 64); X += __shfl_xor(X, 32, 64)
    RED3(A0); RED3(A1); RED3(A2); RED3(A3);
    RED3(B0); RED3(B1); RED3(B2); RED3(B3);
    RED3(C0); RED3(C1); RED3(C2); RED3(C3);
    RED3(D0); RED3(D1); RED3(D2); RED3(D3);
    float w0 = Wfc[4 * f + 0], w1 = Wfc[4 * f + 1];
    float w2 = Wfc[4 * f + 2], w3 = Wfc[4 * f + 3];
    float g0 = b2[4 * f + 0], g1 = b2[4 * f + 1];
    float g2 = b2[4 * f + 2], g3 = b2[4 * f + 3];
    float dv0 = dinv[vb], dv1 = dinv[vb + 1], dv2 = dinv[vb + 2], dv3 = dinv[vb + 3];
    float p0 = fmaxf(fmaf(dv0, A0, g0), 0.f) * w0 + fmaxf(fmaf(dv0, A1, g1), 0.f) * w1
             + fmaxf(fmaf(dv0, A2, g2), 0.f) * w2 + fmaxf(fmaf(dv0, A3, g3), 0.f) * w3;
    float p1 = fmaxf(fmaf(dv1, B0, g0), 0.f) * w0 + fmaxf(fmaf(dv1, B1, g1), 0.f) * w1
             + fmaxf(fmaf(dv1, B2, g2), 0.f) * w2 + fmaxf(fmaf(dv1, B3, g3), 0.f) * w3;
    float p2 = fmaxf(fmaf(dv2, C0, g0), 0.f) * w0 + fmaxf(fmaf(dv2, C1, g1), 0.f) * w1
             + fmaxf(fmaf(dv2, C2, g2), 0.f) * w2 + fmaxf(fmaf(dv2, C3, g3), 0.f) * w3;
    float p3 = fmaxf(fmaf(dv3, D0, g0), 0.f) * w0 + fmaxf(fmaf(dv3, D1, g1), 0.f) * w1
             + fmaxf(fmaf(dv3, D2, g2), 0.f) * w2 + fmaxf(fmaf(dv3, D3, g3), 0.f) * w3;
#define REDP(X) X += __shfl_xor(X, 1, 64); X += __shfl_xor(X, 2, 64); X += __shfl_xor(X, 4, 64)
    REDP(p0); REDP(p1); REDP(p2); REDP(p3);
    if (lane == 0) {
        float bb = bfc[0];
        out[vb + 0] = p0 + bb;
        out[vb + 1] = p1 + bb;
        out[vb + 2] = p2 + bb;
        out[vb + 3] = p3 + bb;
    }
}

// ============ launch ============

extern "C" void kernel_launch(void* const* d_in, const int* in_sizes, int n_in,
                              void* d_out, int out_size, void* d_ws, size_t ws_size,
                              hipStream_t stream) {
    const float* x   = (const float*)d_in[0];
    const int*   ei  = (const int*)d_in[1];
    const float* W1  = (const float*)d_in[2];
    const float* b1  = (const float*)d_in[3];
    const float* W2  = (const float*)d_in[4];
    const float* b2  = (const float*)d_in[5];
    const float* Wfc = (const float*)d_in[6];
    const float* bfc = (const float*)d_in[7];
    float* out = (float*)d_out;

    const int E = in_sizes[1] / 2;
    const int TOT = E + N_NODES;
    const int* src = ei;
    const int* dst = ei + E;

    // workspace layout (ints)
    int*   ccount  = (int*)d_ws;                   // 256
    int*   cbase   = ccount + 256;                 // 256 (NBKT+1 used)
    int*   bcur    = cbase + 256;                  // 256
    int*   offsets = bcur + 256;                   // N+1
    int*   srt_src = offsets + N_NODES + 1;        // TOT
    size_t bb_off  = (size_t)(srt_src - (int*)d_ws) + TOT;
    bb_off = (bb_off + 1) & ~(size_t)1;            // 8B-align for uint2
    uint2* bktBuf  = (uint2*)((int*)d_ws + bb_off);        // TOT uint2
    float* dinv    = (float*)((int*)d_ws + bb_off + 2 * (size_t)TOT);  // N
    u16*   h1b     = (u16*)(dinv + N_NODES);       // N*64 bf16
    u16*   h2b     = h1b + (size_t)N_NODES * 64;   // N*32 bf16

    const int NCH = (TOT + CH - 1) / CH;

    hipMemsetAsync(ccount, 0, 256 * sizeof(int), stream);
    coarsehist_k<<<NCH, 256, 0, stream>>>(dst, ccount, E, TOT);
    coarsescan_k<<<1, 256, 0, stream>>>(ccount, cbase, bcur, offsets);
    partition_k<<<NCH, 256, 0, stream>>>(src, dst, bcur, bktBuf, E, TOT);
    buildfill_k<<<NBKT, 256, 0, stream>>>(cbase, bktBuf, offsets, dinv, srt_src);

    const int GB1 = (N_NODES / 32 + 3) / 4;   // 782 blocks x 4 waves x 32 rows
    gemm1_k<<<GB1, 256, 0, stream>>>(x, W1, dinv, h1b);

    layer2_k<<<N_NODES / 8, 256, 0, stream>>>(offsets, srt_src, dinv, h1b, b1, W2, h2b);
    layer3_k<<<N_NODES / 16, 256, 0, stream>>>(offsets, srt_src, dinv, h2b, b2, Wfc,
                                               bfc, out);
}